// Round 1
// baseline (4253.687 us; speedup 1.0000x reference)
//
#include <hip/hip_runtime.h>
#include <hip/hip_bf16.h>
#include <math.h>

#define B_ 4
#define S_ 2048
#define D_ 512
#define H_ 8
#define L_ 4
#define DH_ 64
#define MLP_ 2048
#define BLK_ 128
#define NB_ 16
#define NEGINF -1e9f

// ---------------- embed + sinusoid PE ----------------
__global__ __launch_bounds__(128) void k_embed(const int* __restrict__ tokens,
                                               const float* __restrict__ embed,
                                               float* __restrict__ x) {
  int bs = blockIdx.x;            // B*S
  int tid = threadIdx.x;          // 128
  int s = bs & (S_ - 1);
  int tok = tokens[bs];
  const float c = -logf(10000.0f) / (float)D_;
  int d = tid * 4;
  float4 e = *(const float4*)(embed + (size_t)tok * D_ + d);
  float pe[4];
#pragma unroll
  for (int j = 0; j < 4; ++j) {
    int dd = d + j;
    int i2 = dd >> 1;
    float freq = expf(c * (float)(2 * i2));
    float ang = (float)s * freq;
    pe[j] = (dd & 1) ? cosf(ang) : sinf(ang);
  }
  *(float4*)(x + (size_t)bs * D_ + d) =
      make_float4(e.x + pe[0], e.y + pe[1], e.z + pe[2], e.w + pe[3]);
}

// ---------------- layernorm (wave per row) ----------------
__global__ __launch_bounds__(256) void k_ln(const float* __restrict__ x,
                                            const float* __restrict__ sc,
                                            const float* __restrict__ bi,
                                            float* __restrict__ out, int rows) {
  int row = blockIdx.x * 4 + (threadIdx.x >> 6);
  int lane = threadIdx.x & 63;
  if (row >= rows) return;
  const float* xr = x + (size_t)row * D_;
  float v[8];
  float4 a = *(const float4*)(xr + lane * 8);
  float4 b = *(const float4*)(xr + lane * 8 + 4);
  v[0]=a.x; v[1]=a.y; v[2]=a.z; v[3]=a.w; v[4]=b.x; v[5]=b.y; v[6]=b.z; v[7]=b.w;
  float sum = 0.f;
#pragma unroll
  for (int j = 0; j < 8; ++j) sum += v[j];
#pragma unroll
  for (int off = 32; off; off >>= 1) sum += __shfl_xor(sum, off);
  float mean = sum * (1.0f / D_);
  float var = 0.f;
#pragma unroll
  for (int j = 0; j < 8; ++j) { float d = v[j] - mean; var += d * d; }
#pragma unroll
  for (int off = 32; off; off >>= 1) var += __shfl_xor(var, off);
  float rstd = rsqrtf(var * (1.0f / D_) + 1e-6f);
  float o[8];
#pragma unroll
  for (int j = 0; j < 8; ++j) {
    int d = lane * 8 + j;
    o[j] = (v[j] - mean) * rstd * sc[d] + bi[d];
  }
  float* op = out + (size_t)row * D_ + lane * 8;
  *(float4*)op = make_float4(o[0], o[1], o[2], o[3]);
  *(float4*)(op + 4) = make_float4(o[4], o[5], o[6], o[7]);
}

// ---------------- generic fp32 GEMM, 64x64 tile ----------------
__device__ __forceinline__ float gelu_f(float x) {
  float x3 = x * x * x;
  float t = tanhf(0.7978845608028654f * (x + 0.044715f * x3));
  return 0.5f * x * (1.0f + t);
}

enum { EPI_STORE = 0, EPI_ADD = 1, EPI_GELU = 2, EPI_ADDBIAS = 3 };

template <int EPI>
__global__ __launch_bounds__(256) void k_gemm(const float* __restrict__ A,
                                              const float* __restrict__ Bm,
                                              const float* __restrict__ bias,
                                              float* __restrict__ C,
                                              int M, int N, int K, float alpha) {
  __shared__ float As[16][65];
  __shared__ float Bs[16][68];
  int tid = threadIdx.x;
  int tx = tid & 15, ty = tid >> 4;
  int m0 = blockIdx.y * 64, n0 = blockIdx.x * 64;
  int arow = tid >> 2, acol = (tid & 3) * 4;
  int brow = tid >> 4, bcol = (tid & 15) * 4;
  const float* Ap = A + (size_t)(m0 + arow) * K + acol;
  const float* Bp = Bm + (size_t)brow * N + n0 + bcol;
  float acc[4][4] = {};
  for (int k0 = 0; k0 < K; k0 += 16) {
    float4 av = *(const float4*)(Ap + k0);
    float4 bv = *(const float4*)(Bp + (size_t)k0 * N);
    __syncthreads();
    As[acol + 0][arow] = av.x;
    As[acol + 1][arow] = av.y;
    As[acol + 2][arow] = av.z;
    As[acol + 3][arow] = av.w;
    *(float4*)(&Bs[brow][bcol]) = bv;
    __syncthreads();
#pragma unroll
    for (int kk = 0; kk < 16; ++kk) {
      float a[4], b[4];
#pragma unroll
      for (int i = 0; i < 4; ++i) a[i] = As[kk][ty * 4 + i];
#pragma unroll
      for (int j = 0; j < 4; ++j) b[j] = Bs[kk][tx * 4 + j];
#pragma unroll
      for (int i = 0; i < 4; ++i)
#pragma unroll
        for (int j = 0; j < 4; ++j) acc[i][j] += a[i] * b[j];
    }
  }
#pragma unroll
  for (int i = 0; i < 4; ++i) {
    int row = m0 + ty * 4 + i;
    float* cp = C + (size_t)row * N + n0 + tx * 4;
    float4 r;
    if (EPI == EPI_STORE) {
      r = make_float4(acc[i][0] * alpha, acc[i][1] * alpha,
                      acc[i][2] * alpha, acc[i][3] * alpha);
    } else if (EPI == EPI_ADD) {
      float4 cc = *(float4*)cp;
      r = make_float4(cc.x + acc[i][0], cc.y + acc[i][1],
                      cc.z + acc[i][2], cc.w + acc[i][3]);
    } else if (EPI == EPI_GELU) {
      const float* bp = bias + n0 + tx * 4;
      r = make_float4(gelu_f(acc[i][0] + bp[0]), gelu_f(acc[i][1] + bp[1]),
                      gelu_f(acc[i][2] + bp[2]), gelu_f(acc[i][3] + bp[3]));
    } else {
      float4 cc = *(float4*)cp;
      const float* bp = bias + n0 + tx * 4;
      r = make_float4(cc.x + acc[i][0] + bp[0], cc.y + acc[i][1] + bp[1],
                      cc.z + acc[i][2] + bp[2], cc.w + acc[i][3] + bp[3]);
    }
    *(float4*)cp = r;
  }
}

// ---------------- block key sums ----------------
__global__ __launch_bounds__(64) void k_ksum(const float* __restrict__ K,
                                             float* __restrict__ ksum) {
  int id = blockIdx.x;  // B*NB*H
  int h = id & (H_ - 1);
  int n = (id >> 3) & (NB_ - 1);
  int b = id >> 7;
  int f = threadIdx.x;
  float s = 0.f;
  const float* kp = K + (((size_t)(b * S_ + n * BLK_) * H_) + h) * DH_ + f;
  for (int c = 0; c < BLK_; ++c) s += kp[(size_t)c * H_ * DH_];
  ksum[(((size_t)(b * NB_ + n) * H_) + h) * DH_ + f] = s;
}

// ---------------- sort-net logits ----------------
__global__ __launch_bounds__(256) void k_logits(const float* __restrict__ ksum,
                                                const float* __restrict__ sw,
                                                float* __restrict__ logits) {
  int idx = blockIdx.x * 256 + threadIdx.x;  // B*H*NB*NB = 8192
  int m = idx & 15;
  int n = (idx >> 4) & 15;
  int h = (idx >> 8) & 7;
  int b = idx >> 11;
  const float* kp = ksum + (((size_t)(b * NB_ + n) * H_) + h) * DH_;
  const float* wp = sw + (size_t)h * DH_ * NB_ + m;
  float s = 0.f;
#pragma unroll
  for (int d = 0; d < DH_; ++d) s += kp[d] * wp[(size_t)d * NB_];
  logits[idx] = s;
}

// ---------------- sinkhorn (one block per (b,h)) ----------------
__global__ __launch_bounds__(256) void k_sinkhorn(const float* __restrict__ logits,
                                                  float* __restrict__ perm) {
  int bh = blockIdx.x;
  int tid = threadIdx.x;
  int i = tid >> 4, j = tid & 15;
  float la = logits[(size_t)bh * 256 + tid];
  __shared__ float buf[256];
  __shared__ float red[16];
  for (int it = 0; it < 8; ++it) {
    // row logsumexp (over last dim m == j)
    buf[tid] = la;
    __syncthreads();
    if (j == 0) {
      float m = buf[i * 16];
      for (int t = 1; t < 16; ++t) m = fmaxf(m, buf[i * 16 + t]);
      float s = 0.f;
      for (int t = 0; t < 16; ++t) s += expf(buf[i * 16 + t] - m);
      red[i] = m + logf(s);
    }
    __syncthreads();
    la -= red[i];
    // col logsumexp (over dim n == i)
    buf[tid] = la;
    __syncthreads();
    if (tid < 16) {
      float m = buf[tid];
      for (int t = 1; t < 16; ++t) m = fmaxf(m, buf[t * 16 + tid]);
      float s = 0.f;
      for (int t = 0; t < 16; ++t) s += expf(buf[t * 16 + tid] - m);
      red[tid] = m + logf(s);
    }
    __syncthreads();
    la -= red[j];
    __syncthreads();
  }
  perm[(size_t)bh * 256 + tid] = expf(la);
}

// ---------------- permuted key/value blocks + sorted mask ----------------
__global__ __launch_bounds__(256) void k_sortblocks(
    const float* __restrict__ perm, const float* __restrict__ K,
    const float* __restrict__ V, const int* __restrict__ tokens,
    float* __restrict__ SK, float* __restrict__ SV, float* __restrict__ smask) {
  int n = blockIdx.x, h = blockIdx.y, b = blockIdx.z;
  int tid = threadIdx.x;
  __shared__ float pr[NB_];
  if (tid < NB_) pr[tid] = perm[(((size_t)(b * H_ + h) * NB_) + n) * NB_ + tid];
  __syncthreads();
  for (int i4 = tid; i4 < 2048; i4 += 256) {
    int c = i4 >> 4;
    int f4 = (i4 & 15) * 4;
    float4 ak = make_float4(0, 0, 0, 0), av = make_float4(0, 0, 0, 0);
#pragma unroll
    for (int m = 0; m < NB_; ++m) {
      float p = pr[m];
      size_t off = (((size_t)(b * S_ + m * BLK_ + c) * H_) + h) * DH_ + f4;
      float4 kv = *(const float4*)(K + off);
      float4 vv = *(const float4*)(V + off);
      ak.x += p * kv.x; ak.y += p * kv.y; ak.z += p * kv.z; ak.w += p * kv.w;
      av.x += p * vv.x; av.y += p * vv.y; av.z += p * vv.z; av.w += p * vv.w;
    }
    size_t oo = (((size_t)(b * S_ + n * BLK_ + c) * H_) + h) * DH_ + f4;
    *(float4*)(SK + oo) = ak;
    *(float4*)(SV + oo) = av;
  }
  if (tid < BLK_) {
    float s = 0.f;
#pragma unroll
    for (int m = 0; m < NB_; ++m)
      s += pr[m] * ((tokens[b * S_ + m * BLK_ + tid] > 0) ? 1.0f : 0.0f);
    smask[(((size_t)(b * H_ + h) * NB_) + n) * BLK_ + tid] = s;
  }
}

// ---------------- scores + mask bias ----------------
__global__ __launch_bounds__(256) void k_scores(
    const float* __restrict__ Q, const float* __restrict__ K,
    const float* __restrict__ SK, const int* __restrict__ tokens,
    const float* __restrict__ smask, float* __restrict__ attn) {
  int n = blockIdx.x, h = blockIdx.y, b = blockIdx.z;
  int tid = threadIdx.x;
  __shared__ float kc[256 * DH_];
  __shared__ float sbias[256];
  for (int i4 = tid; i4 < 4096; i4 += 256) {
    int r = i4 >> 4;
    int f4 = (i4 & 15) * 4;
    const float* src = (r < BLK_) ? K : SK;
    int s = n * BLK_ + (r & (BLK_ - 1));
    float4 t = *(const float4*)(src + (((size_t)(b * S_ + s) * H_) + h) * DH_ + f4);
    *(float4*)(kc + r * DH_ + f4) = t;
  }
  {
    float mval;
    if (tid < BLK_)
      mval = (tokens[b * S_ + n * BLK_ + tid] > 0) ? 1.0f : 0.0f;
    else
      mval = smask[(((size_t)(b * H_ + h) * NB_) + n) * BLK_ + (tid - BLK_)];
    sbias[tid] = (mval > 0.5f) ? 0.0f : NEGINF;
  }
  __syncthreads();
  int qi = tid & (BLK_ - 1);
  int kh = (tid >> 7) * BLK_;
  const float* qp = Q + (((size_t)(b * S_ + n * BLK_ + qi) * H_) + h) * DH_;
  float qv[DH_];
#pragma unroll
  for (int f = 0; f < DH_; f += 4) {
    float4 t = *(const float4*)(qp + f);
    qv[f] = t.x; qv[f + 1] = t.y; qv[f + 2] = t.z; qv[f + 3] = t.w;
  }
  float* out = attn + ((((size_t)(b * H_ + h) * NB_ + n) * BLK_ + qi) * 256) + kh;
  for (int k = 0; k < BLK_; ++k) {
    const float* kr = kc + (kh + k) * DH_;
    float s = 0.f;
#pragma unroll
    for (int f = 0; f < DH_; ++f) s += qv[f] * kr[f];
    out[k] = s + sbias[kh + k];
  }
}

// ---------------- softmax rows (wave per 256-wide row) ----------------
__global__ __launch_bounds__(256) void k_softmax(float* __restrict__ attn, int nrows) {
  int row = blockIdx.x * 4 + (threadIdx.x >> 6);
  int lane = threadIdx.x & 63;
  if (row >= nrows) return;
  float* rp = attn + (size_t)row * 256;
  float4 v = *(float4*)(rp + lane * 4);
  float m = fmaxf(fmaxf(v.x, v.y), fmaxf(v.z, v.w));
#pragma unroll
  for (int off = 32; off; off >>= 1) m = fmaxf(m, __shfl_xor(m, off));
  float e0 = expf(v.x - m), e1 = expf(v.y - m), e2 = expf(v.z - m), e3 = expf(v.w - m);
  float s = e0 + e1 + e2 + e3;
#pragma unroll
  for (int off = 32; off; off >>= 1) s += __shfl_xor(s, off);
  float inv = 1.0f / s;
  *(float4*)(rp + lane * 4) = make_float4(e0 * inv, e1 * inv, e2 * inv, e3 * inv);
}

// ---------------- attn @ vcat ----------------
__global__ __launch_bounds__(128) void k_pv(const float* __restrict__ attn,
                                            const float* __restrict__ V,
                                            const float* __restrict__ SV,
                                            float* __restrict__ O) {
  int n = blockIdx.x, h = blockIdx.y, b = blockIdx.z;
  int tid = threadIdx.x;
  __shared__ float vc[256 * DH_];
  for (int i4 = tid; i4 < 4096; i4 += 128) {
    int r = i4 >> 4;
    int f4 = (i4 & 15) * 4;
    const float* src = (r < BLK_) ? V : SV;
    int s = n * BLK_ + (r & (BLK_ - 1));
    float4 t = *(const float4*)(src + (((size_t)(b * S_ + s) * H_) + h) * DH_ + f4);
    *(float4*)(vc + r * DH_ + f4) = t;
  }
  __syncthreads();
  const float* arow = attn + ((((size_t)(b * H_ + h) * NB_ + n) * BLK_ + tid) * 256);
  float acc[DH_] = {};
  for (int k = 0; k < 256; k += 4) {
    float4 a4 = *(const float4*)(arow + k);
    const float* v0 = vc + k * DH_;
#pragma unroll
    for (int f = 0; f < DH_; ++f)
      acc[f] += a4.x * v0[f] + a4.y * v0[DH_ + f] + a4.z * v0[2 * DH_ + f] +
                a4.w * v0[3 * DH_ + f];
  }
  float* op = O + (((size_t)(b * S_ + n * BLK_ + tid) * H_) + h) * DH_;
#pragma unroll
  for (int f = 0; f < DH_; f += 4)
    *(float4*)(op + f) = make_float4(acc[f], acc[f + 1], acc[f + 2], acc[f + 3]);
}

// ---------------- launch ----------------
extern "C" void kernel_launch(void* const* d_in, const int* in_sizes, int n_in,
                              void* d_out, int out_size, void* d_ws, size_t ws_size,
                              hipStream_t stream) {
  const int* tokens = (const int*)d_in[0];
  const float* embed = (const float*)d_in[1];
  const float* ln1_s = (const float*)d_in[2];
  const float* ln1_b = (const float*)d_in[3];
  const float* wq = (const float*)d_in[4];
  const float* wk = (const float*)d_in[5];
  const float* wv = (const float*)d_in[6];
  const float* wo = (const float*)d_in[7];
  const float* sortw = (const float*)d_in[8];
  const float* ln2_s = (const float*)d_in[9];
  const float* ln2_b = (const float*)d_in[10];
  const float* w1 = (const float*)d_in[11];
  const float* b1 = (const float*)d_in[12];
  const float* w2 = (const float*)d_in[13];
  const float* b2 = (const float*)d_in[14];
  const float* lnf_s = (const float*)d_in[15];
  const float* lnf_b = (const float*)d_in[16];
  float* out = (float*)d_out;

  const size_t NX = (size_t)B_ * S_ * D_;  // 4,194,304 floats
  float* ws = (float*)d_ws;
  float* X = ws;                 // residual stream
  float* Hb = ws + NX;           // LN outputs; aliased as attention O
  float* Qb = ws + 2 * NX;
  float* Kb = ws + 3 * NX;
  float* Vb = ws + 4 * NX;
  float* SKb = ws + 5 * NX;
  float* SVb = ws + 6 * NX;
  float* ATT = ws + 7 * NX;      // 4*NX; aliased as MLP hidden
  float* HID = ATT;
  float* Ob = Hb;
  float* KS = ws + 11 * NX;                       // B*NB*H*DH
  float* LG = KS + (size_t)B_ * NB_ * H_ * DH_;   // B*H*NB*NB
  float* PM = LG + (size_t)B_ * H_ * NB_ * NB_;
  float* SM = PM + (size_t)B_ * H_ * NB_ * NB_;   // B*H*NB*BLK

  const int rows = B_ * S_;
  const float scale = 0.125f;  // 1/sqrt(DH)

  k_embed<<<B_ * S_, 128, 0, stream>>>(tokens, embed, X);

  for (int l = 0; l < L_; ++l) {
    k_ln<<<rows / 4, 256, 0, stream>>>(X, ln1_s + l * D_, ln1_b + l * D_, Hb, rows);
    dim3 g1(D_ / 64, rows / 64);
    k_gemm<EPI_STORE><<<g1, 256, 0, stream>>>(Hb, wq + (size_t)l * D_ * D_, nullptr, Qb, rows, D_, D_, scale);
    k_gemm<EPI_STORE><<<g1, 256, 0, stream>>>(Hb, wk + (size_t)l * D_ * D_, nullptr, Kb, rows, D_, D_, 1.0f);
    k_gemm<EPI_STORE><<<g1, 256, 0, stream>>>(Hb, wv + (size_t)l * D_ * D_, nullptr, Vb, rows, D_, D_, 1.0f);
    k_ksum<<<B_ * NB_ * H_, 64, 0, stream>>>(Kb, KS);
    k_logits<<<(B_ * H_ * NB_ * NB_) / 256, 256, 0, stream>>>(KS, sortw + (size_t)l * H_ * DH_ * NB_, LG);
    k_sinkhorn<<<B_ * H_, 256, 0, stream>>>(LG, PM);
    dim3 gatt(NB_, H_, B_);
    k_sortblocks<<<gatt, 256, 0, stream>>>(PM, Kb, Vb, tokens, SKb, SVb, SM);
    k_scores<<<gatt, 256, 0, stream>>>(Qb, Kb, SKb, tokens, SM, ATT);
    k_softmax<<<(B_ * H_ * NB_ * BLK_) / 4, 256, 0, stream>>>(ATT, B_ * H_ * NB_ * BLK_);
    k_pv<<<gatt, 128, 0, stream>>>(ATT, Vb, SVb, Ob);
    k_gemm<EPI_ADD><<<g1, 256, 0, stream>>>(Ob, wo + (size_t)l * D_ * D_, nullptr, X, rows, D_, D_, 1.0f);
    k_ln<<<rows / 4, 256, 0, stream>>>(X, ln2_s + l * D_, ln2_b + l * D_, Hb, rows);
    dim3 g2(MLP_ / 64, rows / 64);
    k_gemm<EPI_GELU><<<g2, 256, 0, stream>>>(Hb, w1 + (size_t)l * D_ * MLP_, b1 + (size_t)l * MLP_, HID, rows, MLP_, D_, 1.0f);
    dim3 g3(D_ / 64, rows / 64);
    k_gemm<EPI_ADDBIAS><<<g3, 256, 0, stream>>>(HID, w2 + (size_t)l * MLP_ * D_, b2 + (size_t)l * D_, X, rows, D_, MLP_, 1.0f);
  }
  k_ln<<<rows / 4, 256, 0, stream>>>(X, lnf_s, lnf_b, out, rows);
}

// Round 2
// 1612.410 us; speedup vs baseline: 2.6381x; 2.6381x over previous
//
#include <hip/hip_runtime.h>
#include <math.h>

#define B_ 4
#define S_ 2048
#define D_ 512
#define H_ 8
#define L_ 4
#define DH_ 64
#define MLP_ 2048
#define BLK_ 128
#define NB_ 16
#define NEGINF -1e9f

typedef unsigned short u16;
typedef __attribute__((ext_vector_type(8))) short short8;
typedef __attribute__((ext_vector_type(4))) float f32x4;

__device__ __forceinline__ float bf2f(u16 s) {
  return __uint_as_float(((unsigned)s) << 16);
}
__device__ __forceinline__ u16 f2bf(float f) {
  unsigned u = __float_as_uint(f);
  unsigned r = (u + 0x7FFFu + ((u >> 16) & 1u)) >> 16;
  return (u16)r;
}

__device__ __forceinline__ void gll16(const void* g, void* l) {
  __builtin_amdgcn_global_load_lds(
      (const __attribute__((address_space(1))) unsigned int*)g,
      (__attribute__((address_space(3))) unsigned int*)l, 16, 0, 0);
}

// ---------------- embed + sinusoid PE ----------------
__global__ __launch_bounds__(128) void k_embed(const int* __restrict__ tokens,
                                               const float* __restrict__ embed,
                                               float* __restrict__ x) {
  int bs = blockIdx.x;
  int tid = threadIdx.x;
  int s = bs & (S_ - 1);
  int tok = tokens[bs];
  const float c = -logf(10000.0f) / (float)D_;
  int d = tid * 4;
  float4 e = *(const float4*)(embed + (size_t)tok * D_ + d);
  float pe[4];
#pragma unroll
  for (int j = 0; j < 4; ++j) {
    int dd = d + j;
    int i2 = dd >> 1;
    float freq = expf(c * (float)(2 * i2));
    float ang = (float)s * freq;
    pe[j] = (dd & 1) ? cosf(ang) : sinf(ang);
  }
  *(float4*)(x + (size_t)bs * D_ + d) =
      make_float4(e.x + pe[0], e.y + pe[1], e.z + pe[2], e.w + pe[3]);
}

// ---------------- layernorm (wave per row), templated output ----------------
template <typename OT>
__global__ __launch_bounds__(256) void k_ln(const float* __restrict__ x,
                                            const float* __restrict__ sc,
                                            const float* __restrict__ bi,
                                            OT* __restrict__ out, int rows) {
  int row = blockIdx.x * 4 + (threadIdx.x >> 6);
  int lane = threadIdx.x & 63;
  if (row >= rows) return;
  const float* xr = x + (size_t)row * D_;
  float v[8];
  float4 a = *(const float4*)(xr + lane * 8);
  float4 b = *(const float4*)(xr + lane * 8 + 4);
  v[0]=a.x; v[1]=a.y; v[2]=a.z; v[3]=a.w; v[4]=b.x; v[5]=b.y; v[6]=b.z; v[7]=b.w;
  float sum = 0.f;
#pragma unroll
  for (int j = 0; j < 8; ++j) sum += v[j];
#pragma unroll
  for (int off = 32; off; off >>= 1) sum += __shfl_xor(sum, off);
  float mean = sum * (1.0f / D_);
  float var = 0.f;
#pragma unroll
  for (int j = 0; j < 8; ++j) { float d = v[j] - mean; var += d * d; }
#pragma unroll
  for (int off = 32; off; off >>= 1) var += __shfl_xor(var, off);
  float rstd = rsqrtf(var * (1.0f / D_) + 1e-6f);
  float o[8];
#pragma unroll
  for (int j = 0; j < 8; ++j) {
    int d = lane * 8 + j;
    o[j] = (v[j] - mean) * rstd * sc[d] + bi[d];
  }
  if constexpr (sizeof(OT) == 4) {
    float* op = (float*)out + (size_t)row * D_ + lane * 8;
    *(float4*)op = make_float4(o[0], o[1], o[2], o[3]);
    *(float4*)(op + 4) = make_float4(o[4], o[5], o[6], o[7]);
  } else {
    u16* op = (u16*)out + (size_t)row * D_ + lane * 8;
    short8 o8;
#pragma unroll
    for (int j = 0; j < 8; ++j) o8[j] = (short)f2bf(o[j]);
    *(short8*)op = o8;
  }
}

// ---------------- weight transpose + bf16 convert: W[K][N] -> WT[N][K] ----------------
__global__ __launch_bounds__(256) void k_transp(const float* __restrict__ W,
                                                u16* __restrict__ WT, int K, int N) {
  __shared__ float t[32][33];
  const float* Wl = W + (size_t)blockIdx.z * K * N;
  u16* WTl = WT + (size_t)blockIdx.z * K * N;
  int k0 = blockIdx.x * 32, n0 = blockIdx.y * 32;
  int x = threadIdx.x & 31, y = threadIdx.x >> 5;
#pragma unroll
  for (int yy = y; yy < 32; yy += 8)
    t[yy][x] = Wl[(size_t)(k0 + yy) * N + n0 + x];
  __syncthreads();
#pragma unroll
  for (int yy = y; yy < 32; yy += 8)
    WTl[(size_t)(n0 + yy) * K + k0 + x] = f2bf(t[x][yy]);
}

// ---------------- bf16 MFMA GEMM (m97 structure): A[M][K] * BT[N][K]^T ----------------
__device__ __forceinline__ float gelu_f(float x) {
  float x3 = x * x * x;
  float t = tanhf(0.7978845608028654f * (x + 0.044715f * x3));
  return 0.5f * x * (1.0f + t);
}

enum { EPI_STORE = 0, EPI_ADD = 1, EPI_GELU = 2, EPI_ADDBIAS = 3 };

template <int EPI>
__global__ __launch_bounds__(256) void k_mm(const u16* __restrict__ A,
                                            const u16* __restrict__ BT,
                                            const float* __restrict__ bias,
                                            u16* __restrict__ Cb,
                                            float* __restrict__ Cf,
                                            int M, int N, int K, float alpha) {
  __shared__ u16 Al[128 * 32];
  __shared__ u16 Bl[128 * 32];
  int tid = threadIdx.x;
  int lane = tid & 63;
  int wave = tid >> 6;
  int m0 = blockIdx.y * 128, n0 = blockIdx.x * 128;
  int wm = (wave >> 1) * 64, wn = (wave & 1) * 64;
  int l15 = lane & 15, l4 = lane >> 4;

  const u16* Ag0 = A + (size_t)(m0 + (tid >> 2)) * K + (tid & 3) * 8;
  const u16* Ag1 = Ag0 + (size_t)64 * K;
  const u16* Bg0 = BT + (size_t)(n0 + (tid >> 2)) * K + (tid & 3) * 8;
  const u16* Bg1 = Bg0 + (size_t)64 * K;
  char* AlB = (char*)Al + wave * 1024;
  char* BlB = (char*)Bl + wave * 1024;

  f32x4 zero = {0.f, 0.f, 0.f, 0.f};
  f32x4 acc[4][4];
#pragma unroll
  for (int i = 0; i < 4; ++i)
#pragma unroll
    for (int j = 0; j < 4; ++j) acc[i][j] = zero;

  for (int k0 = 0; k0 < K; k0 += 32) {
    gll16(Ag0 + k0, AlB);
    gll16(Ag1 + k0, AlB + 4096);
    gll16(Bg0 + k0, BlB);
    gll16(Bg1 + k0, BlB + 4096);
    __syncthreads();
    short8 af[4], bf[4];
#pragma unroll
    for (int i = 0; i < 4; ++i)
      af[i] = *(const short8*)(Al + (wm + i * 16 + l15) * 32 + l4 * 8);
#pragma unroll
    for (int j = 0; j < 4; ++j)
      bf[j] = *(const short8*)(Bl + (wn + j * 16 + l15) * 32 + l4 * 8);
#pragma unroll
    for (int i = 0; i < 4; ++i)
#pragma unroll
      for (int j = 0; j < 4; ++j)
        acc[i][j] = __builtin_amdgcn_mfma_f32_16x16x32_bf16(af[i], bf[j], acc[i][j], 0, 0, 0);
    __syncthreads();
  }

#pragma unroll
  for (int i = 0; i < 4; ++i)
#pragma unroll
    for (int j = 0; j < 4; ++j) {
      int col = n0 + wn + j * 16 + l15;
      float bv = (EPI == EPI_GELU || EPI == EPI_ADDBIAS) ? bias[col] : 0.f;
#pragma unroll
      for (int r = 0; r < 4; ++r) {
        int row = m0 + wm + i * 16 + l4 * 4 + r;
        float v = acc[i][j][r];
        if (EPI == EPI_STORE) {
          Cb[(size_t)row * N + col] = f2bf(v * alpha);
        } else if (EPI == EPI_GELU) {
          Cb[(size_t)row * N + col] = f2bf(gelu_f(v + bv));
        } else if (EPI == EPI_ADD) {
          Cf[(size_t)row * N + col] += v;
        } else {
          Cf[(size_t)row * N + col] += v + bv;
        }
      }
    }
}

// ---------------- block key sums (bf16 K) ----------------
__global__ __launch_bounds__(64) void k_ksum(const u16* __restrict__ K,
                                             float* __restrict__ ksum) {
  int id = blockIdx.x;  // B*NB*H
  int h = id & (H_ - 1);
  int n = (id >> 3) & (NB_ - 1);
  int b = id >> 7;
  int f = threadIdx.x;
  float s = 0.f;
  const u16* kp = K + (((size_t)(b * S_ + n * BLK_) * H_) + h) * DH_ + f;
  for (int c = 0; c < BLK_; ++c) s += bf2f(kp[(size_t)c * H_ * DH_]);
  ksum[(((size_t)(b * NB_ + n) * H_) + h) * DH_ + f] = s;
}

// ---------------- sort-net logits ----------------
__global__ __launch_bounds__(256) void k_logits(const float* __restrict__ ksum,
                                                const float* __restrict__ sw,
                                                float* __restrict__ logits) {
  int idx = blockIdx.x * 256 + threadIdx.x;
  int m = idx & 15;
  int n = (idx >> 4) & 15;
  int h = (idx >> 8) & 7;
  int b = idx >> 11;
  const float* kp = ksum + (((size_t)(b * NB_ + n) * H_) + h) * DH_;
  const float* wp = sw + (size_t)h * DH_ * NB_ + m;
  float s = 0.f;
#pragma unroll
  for (int d = 0; d < DH_; ++d) s += kp[d] * wp[(size_t)d * NB_];
  logits[idx] = s;
}

// ---------------- sinkhorn ----------------
__global__ __launch_bounds__(256) void k_sinkhorn(const float* __restrict__ logits,
                                                  float* __restrict__ perm) {
  int bh = blockIdx.x;
  int tid = threadIdx.x;
  int i = tid >> 4, j = tid & 15;
  float la = logits[(size_t)bh * 256 + tid];
  __shared__ float buf[256];
  __shared__ float red[16];
  for (int it = 0; it < 8; ++it) {
    buf[tid] = la;
    __syncthreads();
    if (j == 0) {
      float m = buf[i * 16];
      for (int t = 1; t < 16; ++t) m = fmaxf(m, buf[i * 16 + t]);
      float s = 0.f;
      for (int t = 0; t < 16; ++t) s += expf(buf[i * 16 + t] - m);
      red[i] = m + logf(s);
    }
    __syncthreads();
    la -= red[i];
    buf[tid] = la;
    __syncthreads();
    if (tid < 16) {
      float m = buf[tid];
      for (int t = 1; t < 16; ++t) m = fmaxf(m, buf[t * 16 + tid]);
      float s = 0.f;
      for (int t = 0; t < 16; ++t) s += expf(buf[t * 16 + tid] - m);
      red[tid] = m + logf(s);
    }
    __syncthreads();
    la -= red[j];
    __syncthreads();
  }
  perm[(size_t)bh * 256 + tid] = expf(la);
}

// ---------------- permuted key/value blocks + sorted mask (bf16) ----------------
__global__ __launch_bounds__(256) void k_sortblocks(
    const float* __restrict__ perm, const u16* __restrict__ K,
    const u16* __restrict__ V, const int* __restrict__ tokens,
    u16* __restrict__ SK, u16* __restrict__ SV, float* __restrict__ smask) {
  int n = blockIdx.x, h = blockIdx.y, b = blockIdx.z;
  int tid = threadIdx.x;
  __shared__ float pr[NB_];
  if (tid < NB_) pr[tid] = perm[(((size_t)(b * H_ + h) * NB_) + n) * NB_ + tid];
  __syncthreads();
  for (int it = tid; it < 1024; it += 256) {
    int c = it >> 3;
    int f8 = (it & 7) * 8;
    float ak[8] = {}, av[8] = {};
#pragma unroll
    for (int m = 0; m < NB_; ++m) {
      float p = pr[m];
      size_t off = (((size_t)(b * S_ + m * BLK_ + c) * H_) + h) * DH_ + f8;
      short8 kv = *(const short8*)(K + off);
      short8 vv = *(const short8*)(V + off);
#pragma unroll
      for (int j = 0; j < 8; ++j) {
        ak[j] += p * bf2f((u16)kv[j]);
        av[j] += p * bf2f((u16)vv[j]);
      }
    }
    short8 ok, ov;
#pragma unroll
    for (int j = 0; j < 8; ++j) {
      ok[j] = (short)f2bf(ak[j]);
      ov[j] = (short)f2bf(av[j]);
    }
    size_t oo = (((size_t)(b * S_ + n * BLK_ + c) * H_) + h) * DH_ + f8;
    *(short8*)(SK + oo) = ok;
    *(short8*)(SV + oo) = ov;
  }
  if (tid < BLK_) {
    float s = 0.f;
#pragma unroll
    for (int m = 0; m < NB_; ++m)
      s += pr[m] * ((tokens[b * S_ + m * BLK_ + tid] > 0) ? 1.0f : 0.0f);
    smask[(((size_t)(b * H_ + h) * NB_) + n) * BLK_ + tid] = s;
  }
}

// ---------------- scores + mask bias (bf16 in, fp32 out) ----------------
__global__ __launch_bounds__(256) void k_scores(
    const u16* __restrict__ Q, const u16* __restrict__ K,
    const u16* __restrict__ SK, const int* __restrict__ tokens,
    const float* __restrict__ smask, float* __restrict__ attn) {
  int n = blockIdx.x, h = blockIdx.y, b = blockIdx.z;
  int tid = threadIdx.x;
  __shared__ float kc[256 * DH_];
  __shared__ float sbias[256];
  for (int it = tid; it < 2048; it += 256) {
    int r = it >> 3;
    int f8 = (it & 7) * 8;
    const u16* src = (r < BLK_) ? K : SK;
    int s = n * BLK_ + (r & (BLK_ - 1));
    short8 t8 = *(const short8*)(src + (((size_t)(b * S_ + s) * H_) + h) * DH_ + f8);
    float* dst = kc + r * DH_ + f8;
#pragma unroll
    for (int j = 0; j < 8; ++j) dst[j] = bf2f((u16)t8[j]);
  }
  {
    float mval;
    if (tid < BLK_)
      mval = (tokens[b * S_ + n * BLK_ + tid] > 0) ? 1.0f : 0.0f;
    else
      mval = smask[(((size_t)(b * H_ + h) * NB_) + n) * BLK_ + (tid - BLK_)];
    sbias[tid] = (mval > 0.5f) ? 0.0f : NEGINF;
  }
  __syncthreads();
  int qi = tid & (BLK_ - 1);
  int kh = (tid >> 7) * BLK_;
  const u16* qp = Q + (((size_t)(b * S_ + n * BLK_ + qi) * H_) + h) * DH_;
  float qv[DH_];
#pragma unroll
  for (int f = 0; f < DH_; f += 8) {
    short8 t8 = *(const short8*)(qp + f);
#pragma unroll
    for (int j = 0; j < 8; ++j) qv[f + j] = bf2f((u16)t8[j]);
  }
  float* out = attn + ((((size_t)(b * H_ + h) * NB_ + n) * BLK_ + qi) * 256) + kh;
  for (int k = 0; k < BLK_; ++k) {
    const float* kr = kc + (kh + k) * DH_;
    float s = 0.f;
#pragma unroll
    for (int f = 0; f < DH_; ++f) s += qv[f] * kr[f];
    out[k] = s + sbias[kh + k];
  }
}

// ---------------- softmax rows ----------------
__global__ __launch_bounds__(256) void k_softmax(float* __restrict__ attn, int nrows) {
  int row = blockIdx.x * 4 + (threadIdx.x >> 6);
  int lane = threadIdx.x & 63;
  if (row >= nrows) return;
  float* rp = attn + (size_t)row * 256;
  float4 v = *(float4*)(rp + lane * 4);
  float m = fmaxf(fmaxf(v.x, v.y), fmaxf(v.z, v.w));
#pragma unroll
  for (int off = 32; off; off >>= 1) m = fmaxf(m, __shfl_xor(m, off));
  float e0 = expf(v.x - m), e1 = expf(v.y - m), e2 = expf(v.z - m), e3 = expf(v.w - m);
  float s = e0 + e1 + e2 + e3;
#pragma unroll
  for (int off = 32; off; off >>= 1) s += __shfl_xor(s, off);
  float inv = 1.0f / s;
  *(float4*)(rp + lane * 4) = make_float4(e0 * inv, e1 * inv, e2 * inv, e3 * inv);
}

// ---------------- attn @ vcat (bf16 V, bf16 out) ----------------
__global__ __launch_bounds__(128) void k_pv(const float* __restrict__ attn,
                                            const u16* __restrict__ V,
                                            const u16* __restrict__ SV,
                                            u16* __restrict__ O) {
  int n = blockIdx.x, h = blockIdx.y, b = blockIdx.z;
  int tid = threadIdx.x;
  __shared__ float vc[256 * DH_];
  for (int it = tid; it < 2048; it += 128) {
    int r = it >> 3;
    int f8 = (it & 7) * 8;
    const u16* src = (r < BLK_) ? V : SV;
    int s = n * BLK_ + (r & (BLK_ - 1));
    short8 t8 = *(const short8*)(src + (((size_t)(b * S_ + s) * H_) + h) * DH_ + f8);
    float* dst = vc + r * DH_ + f8;
#pragma unroll
    for (int j = 0; j < 8; ++j) dst[j] = bf2f((u16)t8[j]);
  }
  __syncthreads();
  const float* arow = attn + ((((size_t)(b * H_ + h) * NB_ + n) * BLK_ + tid) * 256);
  float acc[DH_] = {};
  for (int k = 0; k < 256; k += 4) {
    float4 a4 = *(const float4*)(arow + k);
    const float* v0 = vc + k * DH_;
#pragma unroll
    for (int f = 0; f < DH_; ++f)
      acc[f] += a4.x * v0[f] + a4.y * v0[DH_ + f] + a4.z * v0[2 * DH_ + f] +
                a4.w * v0[3 * DH_ + f];
  }
  u16* op = O + (((size_t)(b * S_ + n * BLK_ + tid) * H_) + h) * DH_;
#pragma unroll
  for (int f = 0; f < DH_; f += 8) {
    short8 o8;
#pragma unroll
    for (int j = 0; j < 8; ++j) o8[j] = (short)f2bf(acc[f + j]);
    *(short8*)(op + f) = o8;
  }
}

// ---------------- launch ----------------
extern "C" void kernel_launch(void* const* d_in, const int* in_sizes, int n_in,
                              void* d_out, int out_size, void* d_ws, size_t ws_size,
                              hipStream_t stream) {
  const int* tokens = (const int*)d_in[0];
  const float* embed = (const float*)d_in[1];
  const float* ln1_s = (const float*)d_in[2];
  const float* ln1_b = (const float*)d_in[3];
  const float* wq = (const float*)d_in[4];
  const float* wk = (const float*)d_in[5];
  const float* wv = (const float*)d_in[6];
  const float* wo = (const float*)d_in[7];
  const float* sortw = (const float*)d_in[8];
  const float* ln2_s = (const float*)d_in[9];
  const float* ln2_b = (const float*)d_in[10];
  const float* w1 = (const float*)d_in[11];
  const float* b1 = (const float*)d_in[12];
  const float* w2 = (const float*)d_in[13];
  const float* b2 = (const float*)d_in[14];
  const float* lnf_s = (const float*)d_in[15];
  const float* lnf_b = (const float*)d_in[16];
  float* out = (float*)d_out;

  const size_t NX = (size_t)B_ * S_ * D_;  // 4,194,304
  float* ws = (float*)d_ws;
  float* X = ws;                    // NX f32
  float* ATT = ws + NX;             // 4*NX f32 (B*H*NB*128*256)
  u16* HID = (u16*)ATT;             // alias: B*S*MLP bf16 fits in ATT region
  u16* Hbf = (u16*)(ws + 5 * NX);   // NX bf16
  u16* Qb = Hbf + NX;
  u16* Kb = Qb + NX;
  u16* Vb = Kb + NX;
  u16* SKb = Vb + NX;
  u16* SVb = SKb + NX;
  u16* Ob = Hbf;                    // alias: LN1 output dead by PV time
  float* KS = (float*)(SVb + NX);
  float* LG = KS + (size_t)B_ * NB_ * H_ * DH_;
  float* PM = LG + (size_t)B_ * H_ * NB_ * NB_;
  float* SM = PM + (size_t)B_ * H_ * NB_ * NB_;
  u16* WT = (u16*)(SM + (size_t)B_ * H_ * NB_ * BLK_);
  u16* wqT = WT;                                  // [L][512][512]
  u16* wkT = wqT + (size_t)L_ * D_ * D_;
  u16* wvT = wkT + (size_t)L_ * D_ * D_;
  u16* woT = wvT + (size_t)L_ * D_ * D_;
  u16* w1T = woT + (size_t)L_ * D_ * D_;          // [L][2048][512]
  u16* w2T = w1T + (size_t)L_ * D_ * MLP_;        // [L][512][2048]

  const int rows = B_ * S_;
  const float scale = 0.125f;

  // weight transposes (bf16, [N][K])
  k_transp<<<dim3(16, 16, L_), 256, 0, stream>>>(wq, wqT, D_, D_);
  k_transp<<<dim3(16, 16, L_), 256, 0, stream>>>(wk, wkT, D_, D_);
  k_transp<<<dim3(16, 16, L_), 256, 0, stream>>>(wv, wvT, D_, D_);
  k_transp<<<dim3(16, 16, L_), 256, 0, stream>>>(wo, woT, D_, D_);
  k_transp<<<dim3(16, 64, L_), 256, 0, stream>>>(w1, w1T, D_, MLP_);
  k_transp<<<dim3(64, 16, L_), 256, 0, stream>>>(w2, w2T, MLP_, D_);

  k_embed<<<B_ * S_, 128, 0, stream>>>(tokens, embed, X);

  for (int l = 0; l < L_; ++l) {
    k_ln<u16><<<rows / 4, 256, 0, stream>>>(X, ln1_s + l * D_, ln1_b + l * D_, Hbf, rows);
    dim3 gqkv(D_ / 128, rows / 128);
    k_mm<EPI_STORE><<<gqkv, 256, 0, stream>>>(Hbf, wqT + (size_t)l * D_ * D_, nullptr, Qb, nullptr, rows, D_, D_, scale);
    k_mm<EPI_STORE><<<gqkv, 256, 0, stream>>>(Hbf, wkT + (size_t)l * D_ * D_, nullptr, Kb, nullptr, rows, D_, D_, 1.0f);
    k_mm<EPI_STORE><<<gqkv, 256, 0, stream>>>(Hbf, wvT + (size_t)l * D_ * D_, nullptr, Vb, nullptr, rows, D_, D_, 1.0f);
    k_ksum<<<B_ * NB_ * H_, 64, 0, stream>>>(Kb, KS);
    k_logits<<<(B_ * H_ * NB_ * NB_) / 256, 256, 0, stream>>>(KS, sortw + (size_t)l * H_ * DH_ * NB_, LG);
    k_sinkhorn<<<B_ * H_, 256, 0, stream>>>(LG, PM);
    dim3 gatt(NB_, H_, B_);
    k_sortblocks<<<gatt, 256, 0, stream>>>(PM, Kb, Vb, tokens, SKb, SVb, SM);
    k_scores<<<gatt, 256, 0, stream>>>(Qb, Kb, SKb, tokens, SM, ATT);
    k_softmax<<<(B_ * H_ * NB_ * BLK_) / 4, 256, 0, stream>>>(ATT, B_ * H_ * NB_ * BLK_);
    k_pv<<<gatt, 128, 0, stream>>>(ATT, Vb, SVb, Ob);
    k_mm<EPI_ADD><<<gqkv, 256, 0, stream>>>(Ob, woT + (size_t)l * D_ * D_, nullptr, nullptr, X, rows, D_, D_, 1.0f);
    k_ln<u16><<<rows / 4, 256, 0, stream>>>(X, ln2_s + l * D_, ln2_b + l * D_, Hbf, rows);
    dim3 g2(MLP_ / 128, rows / 128);
    k_mm<EPI_GELU><<<g2, 256, 0, stream>>>(Hbf, w1T + (size_t)l * D_ * MLP_, b1 + (size_t)l * MLP_, HID, nullptr, rows, MLP_, D_, 1.0f);
    dim3 g3(D_ / 128, rows / 128);
    k_mm<EPI_ADDBIAS><<<g3, 256, 0, stream>>>(HID, w2T + (size_t)l * MLP_ * D_, b2 + (size_t)l * D_, nullptr, X, rows, D_, MLP_, 1.0f);
  }
  k_ln<float><<<rows / 4, 256, 0, stream>>>(X, lnf_s, lnf_b, out, rows);
}

// Round 3
// 1125.740 us; speedup vs baseline: 3.7786x; 1.4323x over previous
//
#include <hip/hip_runtime.h>
#include <math.h>

#define B_ 4
#define S_ 2048
#define D_ 512
#define H_ 8
#define L_ 4
#define DH_ 64
#define MLP_ 2048
#define BLK_ 128
#define NB_ 16
#define NEGINF -1e9f

typedef unsigned short u16;
typedef __attribute__((ext_vector_type(8))) short short8;
typedef __attribute__((ext_vector_type(4))) short short4v;
typedef __attribute__((ext_vector_type(4))) float f32x4;

__device__ __forceinline__ float bf2f(u16 s) {
  return __uint_as_float(((unsigned)s) << 16);
}
__device__ __forceinline__ u16 f2bf(float f) {
  unsigned u = __float_as_uint(f);
  unsigned r = (u + 0x7FFFu + ((u >> 16) & 1u)) >> 16;
  return (u16)r;
}

__device__ __forceinline__ void gll16(const void* g, void* l) {
  __builtin_amdgcn_global_load_lds(
      (const __attribute__((address_space(1))) unsigned int*)g,
      (__attribute__((address_space(3))) unsigned int*)l, 16, 0, 0);
}

// ---------------- embed + sinusoid PE ----------------
__global__ __launch_bounds__(128) void k_embed(const int* __restrict__ tokens,
                                               const float* __restrict__ embed,
                                               float* __restrict__ x) {
  int bs = blockIdx.x;
  int tid = threadIdx.x;
  int s = bs & (S_ - 1);
  int tok = tokens[bs];
  const float c = -logf(10000.0f) / (float)D_;
  int d = tid * 4;
  float4 e = *(const float4*)(embed + (size_t)tok * D_ + d);
  float pe[4];
#pragma unroll
  for (int j = 0; j < 4; ++j) {
    int dd = d + j;
    int i2 = dd >> 1;
    float freq = expf(c * (float)(2 * i2));
    float ang = (float)s * freq;
    pe[j] = (dd & 1) ? cosf(ang) : sinf(ang);
  }
  *(float4*)(x + (size_t)bs * D_ + d) =
      make_float4(e.x + pe[0], e.y + pe[1], e.z + pe[2], e.w + pe[3]);
}

// ---------------- layernorm (wave per row), templated output ----------------
template <typename OT>
__global__ __launch_bounds__(256) void k_ln(const float* __restrict__ x,
                                            const float* __restrict__ sc,
                                            const float* __restrict__ bi,
                                            OT* __restrict__ out, int rows) {
  int row = blockIdx.x * 4 + (threadIdx.x >> 6);
  int lane = threadIdx.x & 63;
  if (row >= rows) return;
  const float* xr = x + (size_t)row * D_;
  float v[8];
  float4 a = *(const float4*)(xr + lane * 8);
  float4 b = *(const float4*)(xr + lane * 8 + 4);
  v[0]=a.x; v[1]=a.y; v[2]=a.z; v[3]=a.w; v[4]=b.x; v[5]=b.y; v[6]=b.z; v[7]=b.w;
  float sum = 0.f;
#pragma unroll
  for (int j = 0; j < 8; ++j) sum += v[j];
#pragma unroll
  for (int off = 32; off; off >>= 1) sum += __shfl_xor(sum, off);
  float mean = sum * (1.0f / D_);
  float var = 0.f;
#pragma unroll
  for (int j = 0; j < 8; ++j) { float d = v[j] - mean; var += d * d; }
#pragma unroll
  for (int off = 32; off; off >>= 1) var += __shfl_xor(var, off);
  float rstd = rsqrtf(var * (1.0f / D_) + 1e-6f);
  float o[8];
#pragma unroll
  for (int j = 0; j < 8; ++j) {
    int d = lane * 8 + j;
    o[j] = (v[j] - mean) * rstd * sc[d] + bi[d];
  }
  if constexpr (sizeof(OT) == 4) {
    float* op = (float*)out + (size_t)row * D_ + lane * 8;
    *(float4*)op = make_float4(o[0], o[1], o[2], o[3]);
    *(float4*)(op + 4) = make_float4(o[4], o[5], o[6], o[7]);
  } else {
    u16* op = (u16*)out + (size_t)row * D_ + lane * 8;
    short8 o8;
#pragma unroll
    for (int j = 0; j < 8; ++j) o8[j] = (short)f2bf(o[j]);
    *(short8*)op = o8;
  }
}

// ---------------- weight transpose + bf16 convert: W[K][N] -> WT[N][K] ----------------
__global__ __launch_bounds__(256) void k_transp(const float* __restrict__ W,
                                                u16* __restrict__ WT, int K, int N) {
  __shared__ float t[32][33];
  const float* Wl = W + (size_t)blockIdx.z * K * N;
  u16* WTl = WT + (size_t)blockIdx.z * K * N;
  int k0 = blockIdx.x * 32, n0 = blockIdx.y * 32;
  int x = threadIdx.x & 31, y = threadIdx.x >> 5;
#pragma unroll
  for (int yy = y; yy < 32; yy += 8)
    t[yy][x] = Wl[(size_t)(k0 + yy) * N + n0 + x];
  __syncthreads();
#pragma unroll
  for (int yy = y; yy < 32; yy += 8)
    WTl[(size_t)(n0 + yy) * K + k0 + x] = f2bf(t[x][yy]);
}

// ---------------- bf16 MFMA GEMM (m97 structure): A[M][K] * BT[N][K]^T ----------------
__device__ __forceinline__ float gelu_f(float x) {
  float x3 = x * x * x;
  float t = tanhf(0.7978845608028654f * (x + 0.044715f * x3));
  return 0.5f * x * (1.0f + t);
}

enum { EPI_STORE = 0, EPI_ADD = 1, EPI_GELU = 2, EPI_ADDBIAS = 3 };

template <int EPI>
__global__ __launch_bounds__(256) void k_mm(const u16* __restrict__ A,
                                            const u16* __restrict__ BT,
                                            const float* __restrict__ bias,
                                            u16* __restrict__ Cb,
                                            float* __restrict__ Cf,
                                            int M, int N, int K, float alpha) {
  __shared__ u16 Al[128 * 32];
  __shared__ u16 Bl[128 * 32];
  int tid = threadIdx.x;
  int lane = tid & 63;
  int wave = tid >> 6;
  int m0 = blockIdx.y * 128, n0 = blockIdx.x * 128;
  int wm = (wave >> 1) * 64, wn = (wave & 1) * 64;
  int l15 = lane & 15, l4 = lane >> 4;

  const u16* Ag0 = A + (size_t)(m0 + (tid >> 2)) * K + (tid & 3) * 8;
  const u16* Ag1 = Ag0 + (size_t)64 * K;
  const u16* Bg0 = BT + (size_t)(n0 + (tid >> 2)) * K + (tid & 3) * 8;
  const u16* Bg1 = Bg0 + (size_t)64 * K;
  char* AlB = (char*)Al + wave * 1024;
  char* BlB = (char*)Bl + wave * 1024;

  f32x4 zero = {0.f, 0.f, 0.f, 0.f};
  f32x4 acc[4][4];
#pragma unroll
  for (int i = 0; i < 4; ++i)
#pragma unroll
    for (int j = 0; j < 4; ++j) acc[i][j] = zero;

  for (int k0 = 0; k0 < K; k0 += 32) {
    gll16(Ag0 + k0, AlB);
    gll16(Ag1 + k0, AlB + 4096);
    gll16(Bg0 + k0, BlB);
    gll16(Bg1 + k0, BlB + 4096);
    __syncthreads();
    short8 af[4], bf[4];
#pragma unroll
    for (int i = 0; i < 4; ++i)
      af[i] = *(const short8*)(Al + (wm + i * 16 + l15) * 32 + l4 * 8);
#pragma unroll
    for (int j = 0; j < 4; ++j)
      bf[j] = *(const short8*)(Bl + (wn + j * 16 + l15) * 32 + l4 * 8);
#pragma unroll
    for (int i = 0; i < 4; ++i)
#pragma unroll
      for (int j = 0; j < 4; ++j)
        acc[i][j] = __builtin_amdgcn_mfma_f32_16x16x32_bf16(af[i], bf[j], acc[i][j], 0, 0, 0);
    __syncthreads();
  }

#pragma unroll
  for (int i = 0; i < 4; ++i)
#pragma unroll
    for (int j = 0; j < 4; ++j) {
      int col = n0 + wn + j * 16 + l15;
      float bv = (EPI == EPI_GELU || EPI == EPI_ADDBIAS) ? bias[col] : 0.f;
#pragma unroll
      for (int r = 0; r < 4; ++r) {
        int row = m0 + wm + i * 16 + l4 * 4 + r;
        float v = acc[i][j][r];
        if (EPI == EPI_STORE) {
          Cb[(size_t)row * N + col] = f2bf(v * alpha);
        } else if (EPI == EPI_GELU) {
          Cb[(size_t)row * N + col] = f2bf(gelu_f(v + bv));
        } else if (EPI == EPI_ADD) {
          Cf[(size_t)row * N + col] += v;
        } else {
          Cf[(size_t)row * N + col] += v + bv;
        }
      }
    }
}

// ---------------- block key sums (bf16 K) ----------------
__global__ __launch_bounds__(64) void k_ksum(const u16* __restrict__ K,
                                             float* __restrict__ ksum) {
  int id = blockIdx.x;  // B*NB*H
  int h = id & (H_ - 1);
  int n = (id >> 3) & (NB_ - 1);
  int b = id >> 7;
  int f = threadIdx.x;
  float s = 0.f;
  const u16* kp = K + (((size_t)(b * S_ + n * BLK_) * H_) + h) * DH_ + f;
  for (int c = 0; c < BLK_; ++c) s += bf2f(kp[(size_t)c * H_ * DH_]);
  ksum[(((size_t)(b * NB_ + n) * H_) + h) * DH_ + f] = s;
}

// ---------------- sort-net logits ----------------
__global__ __launch_bounds__(256) void k_logits(const float* __restrict__ ksum,
                                                const float* __restrict__ sw,
                                                float* __restrict__ logits) {
  int idx = blockIdx.x * 256 + threadIdx.x;
  int m = idx & 15;
  int n = (idx >> 4) & 15;
  int h = (idx >> 8) & 7;
  int b = idx >> 11;
  const float* kp = ksum + (((size_t)(b * NB_ + n) * H_) + h) * DH_;
  const float* wp = sw + (size_t)h * DH_ * NB_ + m;
  float s = 0.f;
#pragma unroll
  for (int d = 0; d < DH_; ++d) s += kp[d] * wp[(size_t)d * NB_];
  logits[idx] = s;
}

// ---------------- sinkhorn ----------------
__global__ __launch_bounds__(256) void k_sinkhorn(const float* __restrict__ logits,
                                                  float* __restrict__ perm) {
  int bh = blockIdx.x;
  int tid = threadIdx.x;
  int i = tid >> 4, j = tid & 15;
  float la = logits[(size_t)bh * 256 + tid];
  __shared__ float buf[256];
  __shared__ float red[16];
  for (int it = 0; it < 8; ++it) {
    buf[tid] = la;
    __syncthreads();
    if (j == 0) {
      float m = buf[i * 16];
      for (int t = 1; t < 16; ++t) m = fmaxf(m, buf[i * 16 + t]);
      float s = 0.f;
      for (int t = 0; t < 16; ++t) s += expf(buf[i * 16 + t] - m);
      red[i] = m + logf(s);
    }
    __syncthreads();
    la -= red[i];
    buf[tid] = la;
    __syncthreads();
    if (tid < 16) {
      float m = buf[tid];
      for (int t = 1; t < 16; ++t) m = fmaxf(m, buf[t * 16 + tid]);
      float s = 0.f;
      for (int t = 0; t < 16; ++t) s += expf(buf[t * 16 + tid] - m);
      red[tid] = m + logf(s);
    }
    __syncthreads();
    la -= red[j];
    __syncthreads();
  }
  perm[(size_t)bh * 256 + tid] = expf(la);
}

// ---------------- permuted key/value blocks + sorted mask (bf16) ----------------
__global__ __launch_bounds__(256) void k_sortblocks(
    const float* __restrict__ perm, const u16* __restrict__ K,
    const u16* __restrict__ V, const int* __restrict__ tokens,
    u16* __restrict__ SK, u16* __restrict__ SV, float* __restrict__ smask) {
  int n = blockIdx.x, h = blockIdx.y, b = blockIdx.z;
  int tid = threadIdx.x;
  __shared__ float pr[NB_];
  if (tid < NB_) pr[tid] = perm[(((size_t)(b * H_ + h) * NB_) + n) * NB_ + tid];
  __syncthreads();
  for (int it = tid; it < 1024; it += 256) {
    int c = it >> 3;
    int f8 = (it & 7) * 8;
    float ak[8] = {}, av[8] = {};
#pragma unroll
    for (int m = 0; m < NB_; ++m) {
      float p = pr[m];
      size_t off = (((size_t)(b * S_ + m * BLK_ + c) * H_) + h) * DH_ + f8;
      short8 kv = *(const short8*)(K + off);
      short8 vv = *(const short8*)(V + off);
#pragma unroll
      for (int j = 0; j < 8; ++j) {
        ak[j] += p * bf2f((u16)kv[j]);
        av[j] += p * bf2f((u16)vv[j]);
      }
    }
    short8 ok, ov;
#pragma unroll
    for (int j = 0; j < 8; ++j) {
      ok[j] = (short)f2bf(ak[j]);
      ov[j] = (short)f2bf(av[j]);
    }
    size_t oo = (((size_t)(b * S_ + n * BLK_ + c) * H_) + h) * DH_ + f8;
    *(short8*)(SK + oo) = ok;
    *(short8*)(SV + oo) = ov;
  }
  if (tid < BLK_) {
    float s = 0.f;
#pragma unroll
    for (int m = 0; m < NB_; ++m)
      s += pr[m] * ((tokens[b * S_ + m * BLK_ + tid] > 0) ? 1.0f : 0.0f);
    smask[(((size_t)(b * H_ + h) * NB_) + n) * BLK_ + tid] = s;
  }
}

// ---------------- fused attention: scores + mask + softmax + PV (MFMA) ----------------
// 8 waves; wave w owns q rows [w*16, w*16+16). Swapped QK^T: St = mfma(Kcat, Q),
// so lane holds a full score row (q = lane&15 within wave) -> in-register softmax.
__global__ __launch_bounds__(512) void k_attn(
    const u16* __restrict__ Q, const u16* __restrict__ Kg, const u16* __restrict__ SK,
    const u16* __restrict__ Vg, const u16* __restrict__ SV,
    const int* __restrict__ tokens, const float* __restrict__ smask,
    u16* __restrict__ O) {
  int n = blockIdx.x, h = blockIdx.y, b = blockIdx.z;
  int tid = threadIdx.x;
  int lane = tid & 63;
  int w = tid >> 6;
  int l15 = lane & 15, l4 = lane >> 4;

  __shared__ u16 KV[16384];   // Kcat [256 kcat][64 dh] swizzled; later V^T [64][256]
  __shared__ u16 Pl[32768];   // P [128 q][256 k] bf16, q-XOR swizzled 8B slots
  __shared__ float sbias[256];

  // ---- V -> registers (issue early; LDS-write after QK phase, T14) ----
  short8 vreg[4];
  int vrow;
  {
    vrow = tid & 255;                 // kcat row
    int rl = vrow & 127;
    const u16* vsrc = (vrow < BLK_) ? Vg : SV;
    const u16* vbase = vsrc + (((size_t)(b * S_ + n * BLK_ + rl) * H_) + h) * DH_;
    int fh = (tid >> 8) * 8;
#pragma unroll
    for (int s = 0; s < 4; ++s)
      vreg[s] = *(const short8*)(vbase + s * 16 + fh);
  }

  // ---- Kcat -> LDS (global_load_lds, source pre-swizzled: rule #21) ----
#pragma unroll
  for (int s = 0; s < 4; ++s) {
    int c = s * 512 + tid;            // 16B chunk id, 0..2047
    int r = c >> 3;                   // kcat row
    int fs = (c & 7) ^ (r & 7);       // swizzled 16B slot in source
    const u16* ksrc = (r < BLK_) ? Kg : SK;
    gll16(ksrc + (((size_t)(b * S_ + n * BLK_ + (r & 127)) * H_) + h) * DH_ + fs * 8,
          (char*)KV + (s * 512 + w * 64) * 16);
  }

  // ---- Q fragments straight from global (B-operand, held in regs) ----
  short8 qf0, qf1;
  {
    const u16* qp = Q + (((size_t)(b * S_ + n * BLK_ + w * 16 + l15) * H_) + h) * DH_ + l4 * 8;
    qf0 = *(const short8*)(qp);
    qf1 = *(const short8*)(qp + 32);
  }

  // ---- mask bias ----
  if (tid < 256) {
    float mval = (tid < BLK_)
        ? ((tokens[b * S_ + n * BLK_ + tid] > 0) ? 1.f : 0.f)
        : smask[(((size_t)(b * H_ + h) * NB_) + n) * BLK_ + (tid - BLK_)];
    sbias[tid] = (mval > 0.5f) ? 0.f : NEGINF;
  }
  __syncthreads();

  // ---- QK^T (swapped): St[kcat][q] ----
  f32x4 zero = {0.f, 0.f, 0.f, 0.f};
  f32x4 st[16];
#pragma unroll
  for (int m = 0; m < 16; ++m) st[m] = zero;
#pragma unroll
  for (int m = 0; m < 16; ++m) {
    int arow = m * 16 + l15;
    const u16* kb = KV + arow * 64;
    int sw = arow & 7;
    short8 a0 = *(const short8*)(kb + ((l4 ^ sw) * 8));
    short8 a1 = *(const short8*)(kb + (((4 + l4) ^ sw) * 8));
    st[m] = __builtin_amdgcn_mfma_f32_16x16x32_bf16(a0, qf0, st[m], 0, 0, 0);
    st[m] = __builtin_amdgcn_mfma_f32_16x16x32_bf16(a1, qf1, st[m], 0, 0, 0);
  }

  // ---- softmax in-register: lane owns k = m*16 + l4*4 + r for q = w*16+l15 ----
  float mx = -3.0e38f;
#pragma unroll
  for (int m = 0; m < 16; ++m)
#pragma unroll
    for (int r = 0; r < 4; ++r) {
      st[m][r] += sbias[m * 16 + l4 * 4 + r];
      mx = fmaxf(mx, st[m][r]);
    }
  mx = fmaxf(mx, __shfl_xor(mx, 16));
  mx = fmaxf(mx, __shfl_xor(mx, 32));
  float sum = 0.f;
#pragma unroll
  for (int m = 0; m < 16; ++m)
#pragma unroll
    for (int r = 0; r < 4; ++r) {
      float e = __expf(st[m][r] - mx);
      st[m][r] = e;
      sum += e;
    }
  sum += __shfl_xor(sum, 16);
  sum += __shfl_xor(sum, 32);
  float inv = 1.0f / sum;

  // ---- P -> LDS (bf16, q-XOR swizzle; k = slot*4 + r) ----
  int q = w * 16 + l15;
  int qx = q & 31;
#pragma unroll
  for (int m = 0; m < 16; ++m) {
    short4v p4;
#pragma unroll
    for (int r = 0; r < 4; ++r) p4[r] = (short)f2bf(st[m][r] * inv);
    int slot = (m * 4 + l4) ^ qx;
    *(short4v*)(Pl + q * 256 + slot * 4) = p4;
  }
  __syncthreads();

  // ---- V^T into KV (Kcat dead now); 16B-slot swizzle by (d&7) ----
  {
    int fh = (tid >> 8) * 8;
#pragma unroll
    for (int s = 0; s < 4; ++s) {
#pragma unroll
      for (int j = 0; j < 8; ++j) {
        int d = s * 16 + fh + j;
        KV[d * 256 + (((vrow >> 3) ^ (d & 7)) * 8) + (vrow & 7)] = (u16)vreg[s][j];
      }
    }
  }
  __syncthreads();

  // ---- PV: O[q][dh] = P · V ----
  f32x4 oacc[4];
#pragma unroll
  for (int nf = 0; nf < 4; ++nf) oacc[nf] = zero;
#pragma unroll
  for (int kk = 0; kk < 8; ++kk) {
    int s0 = (kk * 8 + l4 * 2) ^ qx;
    int s1 = (kk * 8 + l4 * 2 + 1) ^ qx;
    short4v a0 = *(const short4v*)(Pl + q * 256 + s0 * 4);
    short4v a1 = *(const short4v*)(Pl + q * 256 + s1 * 4);
    short8 af;
#pragma unroll
    for (int j = 0; j < 4; ++j) { af[j] = a0[j]; af[4 + j] = a1[j]; }
#pragma unroll
    for (int nf = 0; nf < 4; ++nf) {
      int d = nf * 16 + l15;
      short8 bf = *(const short8*)(KV + d * 256 + (((kk * 4 + l4) ^ (d & 7)) * 8));
      oacc[nf] = __builtin_amdgcn_mfma_f32_16x16x32_bf16(af, bf, oacc[nf], 0, 0, 0);
    }
  }

  // ---- store O (bf16) ----
  u16* ob = O + (((size_t)(b * S_ + n * BLK_) * H_) + h) * DH_;
#pragma unroll
  for (int nf = 0; nf < 4; ++nf) {
    int d = nf * 16 + l15;
#pragma unroll
    for (int r = 0; r < 4; ++r) {
      int qq = w * 16 + l4 * 4 + r;
      ob[(size_t)qq * (H_ * DH_) + d] = f2bf(oacc[nf][r]);
    }
  }
}

// ---------------- launch ----------------
extern "C" void kernel_launch(void* const* d_in, const int* in_sizes, int n_in,
                              void* d_out, int out_size, void* d_ws, size_t ws_size,
                              hipStream_t stream) {
  const int* tokens = (const int*)d_in[0];
  const float* embed = (const float*)d_in[1];
  const float* ln1_s = (const float*)d_in[2];
  const float* ln1_b = (const float*)d_in[3];
  const float* wq = (const float*)d_in[4];
  const float* wk = (const float*)d_in[5];
  const float* wv = (const float*)d_in[6];
  const float* wo = (const float*)d_in[7];
  const float* sortw = (const float*)d_in[8];
  const float* ln2_s = (const float*)d_in[9];
  const float* ln2_b = (const float*)d_in[10];
  const float* w1 = (const float*)d_in[11];
  const float* b1 = (const float*)d_in[12];
  const float* w2 = (const float*)d_in[13];
  const float* b2 = (const float*)d_in[14];
  const float* lnf_s = (const float*)d_in[15];
  const float* lnf_b = (const float*)d_in[16];
  float* out = (float*)d_out;

  const size_t NX = (size_t)B_ * S_ * D_;  // 4,194,304
  float* ws = (float*)d_ws;
  float* X = ws;                    // NX f32
  float* ATT = ws + NX;             // 4*NX f32 region; MLP hidden aliases here
  u16* HID = (u16*)ATT;
  u16* Hbf = (u16*)(ws + 5 * NX);   // NX bf16
  u16* Qb = Hbf + NX;
  u16* Kb = Qb + NX;
  u16* Vb = Kb + NX;
  u16* SKb = Vb + NX;
  u16* SVb = SKb + NX;
  u16* Ob = Hbf;                    // alias: LN1 output dead by PV time
  float* KS = (float*)(SVb + NX);
  float* LG = KS + (size_t)B_ * NB_ * H_ * DH_;
  float* PM = LG + (size_t)B_ * H_ * NB_ * NB_;
  float* SM = PM + (size_t)B_ * H_ * NB_ * NB_;
  u16* WT = (u16*)(SM + (size_t)B_ * H_ * NB_ * BLK_);
  u16* wqT = WT;                                  // [L][512][512]
  u16* wkT = wqT + (size_t)L_ * D_ * D_;
  u16* wvT = wkT + (size_t)L_ * D_ * D_;
  u16* woT = wvT + (size_t)L_ * D_ * D_;
  u16* w1T = woT + (size_t)L_ * D_ * D_;          // [L][2048][512]
  u16* w2T = w1T + (size_t)L_ * D_ * MLP_;        // [L][512][2048]

  const int rows = B_ * S_;
  const float scale = 0.125f;

  // weight transposes (bf16, [N][K])
  k_transp<<<dim3(16, 16, L_), 256, 0, stream>>>(wq, wqT, D_, D_);
  k_transp<<<dim3(16, 16, L_), 256, 0, stream>>>(wk, wkT, D_, D_);
  k_transp<<<dim3(16, 16, L_), 256, 0, stream>>>(wv, wvT, D_, D_);
  k_transp<<<dim3(16, 16, L_), 256, 0, stream>>>(wo, woT, D_, D_);
  k_transp<<<dim3(16, 64, L_), 256, 0, stream>>>(w1, w1T, D_, MLP_);
  k_transp<<<dim3(64, 16, L_), 256, 0, stream>>>(w2, w2T, MLP_, D_);

  k_embed<<<B_ * S_, 128, 0, stream>>>(tokens, embed, X);

  for (int l = 0; l < L_; ++l) {
    k_ln<u16><<<rows / 4, 256, 0, stream>>>(X, ln1_s + l * D_, ln1_b + l * D_, Hbf, rows);
    dim3 gqkv(D_ / 128, rows / 128);
    k_mm<EPI_STORE><<<gqkv, 256, 0, stream>>>(Hbf, wqT + (size_t)l * D_ * D_, nullptr, Qb, nullptr, rows, D_, D_, scale);
    k_mm<EPI_STORE><<<gqkv, 256, 0, stream>>>(Hbf, wkT + (size_t)l * D_ * D_, nullptr, Kb, nullptr, rows, D_, D_, 1.0f);
    k_mm<EPI_STORE><<<gqkv, 256, 0, stream>>>(Hbf, wvT + (size_t)l * D_ * D_, nullptr, Vb, nullptr, rows, D_, D_, 1.0f);
    k_ksum<<<B_ * NB_ * H_, 64, 0, stream>>>(Kb, KS);
    k_logits<<<(B_ * H_ * NB_ * NB_) / 256, 256, 0, stream>>>(KS, sortw + (size_t)l * H_ * DH_ * NB_, LG);
    k_sinkhorn<<<B_ * H_, 256, 0, stream>>>(LG, PM);
    dim3 gatt(NB_, H_, B_);
    k_sortblocks<<<gatt, 256, 0, stream>>>(PM, Kb, Vb, tokens, SKb, SVb, SM);
    k_attn<<<gatt, 512, 0, stream>>>(Qb, Kb, SKb, Vb, SVb, tokens, SM, Ob);
    k_mm<EPI_ADD><<<gqkv, 256, 0, stream>>>(Ob, woT + (size_t)l * D_ * D_, nullptr, nullptr, X, rows, D_, D_, 1.0f);
    k_ln<u16><<<rows / 4, 256, 0, stream>>>(X, ln2_s + l * D_, ln2_b + l * D_, Hbf, rows);
    dim3 g2(MLP_ / 128, rows / 128);
    k_mm<EPI_GELU><<<g2, 256, 0, stream>>>(Hbf, w1T + (size_t)l * D_ * MLP_, b1 + (size_t)l * MLP_, HID, nullptr, rows, MLP_, D_, 1.0f);
    dim3 g3(D_ / 128, rows / 128);
    k_mm<EPI_ADDBIAS><<<g3, 256, 0, stream>>>(HID, w2T + (size_t)l * MLP_ * D_, b2 + (size_t)l * D_, nullptr, X, rows, D_, MLP_, 1.0f);
  }
  k_ln<float><<<rows / 4, 256, 0, stream>>>(X, lnf_s, lnf_b, out, rows);
}

// Round 4
// 972.243 us; speedup vs baseline: 4.3751x; 1.1579x over previous
//
#include <hip/hip_runtime.h>
#include <math.h>

#define B_ 4
#define S_ 2048
#define D_ 512
#define H_ 8
#define L_ 4
#define DH_ 64
#define MLP_ 2048
#define BLK_ 128
#define NB_ 16
#define NEGINF -1e9f
#define NXE ((size_t)B_ * S_ * D_)   // 4,194,304 elements

typedef unsigned short u16;
typedef __attribute__((ext_vector_type(8))) short short8;
typedef __attribute__((ext_vector_type(4))) short short4v;
typedef __attribute__((ext_vector_type(4))) float f32x4;

__device__ __forceinline__ float bf2f(u16 s) {
  return __uint_as_float(((unsigned)s) << 16);
}
__device__ __forceinline__ u16 f2bf(float f) {
  unsigned u = __float_as_uint(f);
  unsigned r = (u + 0x7FFFu + ((u >> 16) & 1u)) >> 16;
  return (u16)r;
}

__device__ __forceinline__ void gll16(const void* g, void* l) {
  __builtin_amdgcn_global_load_lds(
      (const __attribute__((address_space(1))) unsigned int*)g,
      (__attribute__((address_space(3))) unsigned int*)l, 16, 0, 0);
}

// ---------------- embed + sinusoid PE ----------------
__global__ __launch_bounds__(128) void k_embed(const int* __restrict__ tokens,
                                               const float* __restrict__ embed,
                                               float* __restrict__ x) {
  int bs = blockIdx.x;
  int tid = threadIdx.x;
  int s = bs & (S_ - 1);
  int tok = tokens[bs];
  const float c = -logf(10000.0f) / (float)D_;
  int d = tid * 4;
  float4 e = *(const float4*)(embed + (size_t)tok * D_ + d);
  float pe[4];
#pragma unroll
  for (int j = 0; j < 4; ++j) {
    int dd = d + j;
    int i2 = dd >> 1;
    float freq = expf(c * (float)(2 * i2));
    float ang = (float)s * freq;
    pe[j] = (dd & 1) ? cosf(ang) : sinf(ang);
  }
  *(float4*)(x + (size_t)bs * D_ + d) =
      make_float4(e.x + pe[0], e.y + pe[1], e.z + pe[2], e.w + pe[3]);
}

// ---------------- layernorm (wave per row), templated output ----------------
template <typename OT>
__global__ __launch_bounds__(256) void k_ln(const float* __restrict__ x,
                                            const float* __restrict__ sc,
                                            const float* __restrict__ bi,
                                            OT* __restrict__ out, int rows) {
  int row = blockIdx.x * 4 + (threadIdx.x >> 6);
  int lane = threadIdx.x & 63;
  if (row >= rows) return;
  const float* xr = x + (size_t)row * D_;
  float v[8];
  float4 a = *(const float4*)(xr + lane * 8);
  float4 b = *(const float4*)(xr + lane * 8 + 4);
  v[0]=a.x; v[1]=a.y; v[2]=a.z; v[3]=a.w; v[4]=b.x; v[5]=b.y; v[6]=b.z; v[7]=b.w;
  float sum = 0.f;
#pragma unroll
  for (int j = 0; j < 8; ++j) sum += v[j];
#pragma unroll
  for (int off = 32; off; off >>= 1) sum += __shfl_xor(sum, off);
  float mean = sum * (1.0f / D_);
  float var = 0.f;
#pragma unroll
  for (int j = 0; j < 8; ++j) { float d = v[j] - mean; var += d * d; }
#pragma unroll
  for (int off = 32; off; off >>= 1) var += __shfl_xor(var, off);
  float rstd = rsqrtf(var * (1.0f / D_) + 1e-6f);
  float o[8];
#pragma unroll
  for (int j = 0; j < 8; ++j) {
    int d = lane * 8 + j;
    o[j] = (v[j] - mean) * rstd * sc[d] + bi[d];
  }
  if constexpr (sizeof(OT) == 4) {
    float* op = (float*)out + (size_t)row * D_ + lane * 8;
    *(float4*)op = make_float4(o[0], o[1], o[2], o[3]);
    *(float4*)(op + 4) = make_float4(o[4], o[5], o[6], o[7]);
  } else {
    u16* op = (u16*)out + (size_t)row * D_ + lane * 8;
    short8 o8;
#pragma unroll
    for (int j = 0; j < 8; ++j) o8[j] = (short)f2bf(o[j]);
    *(short8*)op = o8;
  }
}

// -------- weight transpose + bf16 convert: W[K][N] -> WT[N][K], strided per z --------
__global__ __launch_bounds__(256) void k_transp(const float* __restrict__ W,
                                                u16* __restrict__ WT, int K, int N,
                                                size_t wStrideZ, size_t tStrideZ) {
  __shared__ float t[32][33];
  const float* Wl = W + (size_t)blockIdx.z * wStrideZ;
  u16* WTl = WT + (size_t)blockIdx.z * tStrideZ;
  int k0 = blockIdx.x * 32, n0 = blockIdx.y * 32;
  int x = threadIdx.x & 31, y = threadIdx.x >> 5;
#pragma unroll
  for (int yy = y; yy < 32; yy += 8)
    t[yy][x] = Wl[(size_t)(k0 + yy) * N + n0 + x];
  __syncthreads();
#pragma unroll
  for (int yy = y; yy < 32; yy += 8)
    WTl[(size_t)(n0 + yy) * K + k0 + x] = f2bf(t[x][yy]);
}

// ---------------- bf16 MFMA GEMM, double-buffered, XCD-swizzled ----------------
__device__ __forceinline__ float gelu_f(float x) {
  float x3 = x * x * x;
  float t = tanhf(0.7978845608028654f * (x + 0.044715f * x3));
  return 0.5f * x * (1.0f + t);
}

enum { EPI_STORE = 0, EPI_ADD = 1, EPI_GELU = 2, EPI_ADDBIAS = 3, EPI_QKV = 4 };

template <int EPI>
__global__ __launch_bounds__(256) void k_mm(const u16* __restrict__ A,
                                            const u16* __restrict__ BT,
                                            const float* __restrict__ bias,
                                            u16* __restrict__ Cb,
                                            float* __restrict__ Cf,
                                            int M, int N, int K, float alpha) {
  __shared__ u16 Al[2][128 * 32];
  __shared__ u16 Bl[2][128 * 32];
  int tid = threadIdx.x;
  int lane = tid & 63;
  int wave = tid >> 6;
  // bijective XCD swizzle (nwg always a multiple of 8 here)
  int nwg = gridDim.x * gridDim.y;
  int bid = blockIdx.y * gridDim.x + blockIdx.x;
  int cpx = nwg >> 3;
  int swz = (bid & 7) * cpx + (bid >> 3);
  int bx = swz % gridDim.x, by = swz / gridDim.x;
  int m0 = by * 128, n0 = bx * 128;
  int wm = (wave >> 1) * 64, wn = (wave & 1) * 64;
  int l15 = lane & 15, l4 = lane >> 4;

  const u16* Ag0 = A + (size_t)(m0 + (tid >> 2)) * K + (tid & 3) * 8;
  const u16* Ag1 = Ag0 + (size_t)64 * K;
  const u16* Bg0 = BT + (size_t)(n0 + (tid >> 2)) * K + (tid & 3) * 8;
  const u16* Bg1 = Bg0 + (size_t)64 * K;

  auto stage = [&](int buf, int k0) {
    char* AlB = (char*)(&Al[buf][0]) + wave * 1024;
    char* BlB = (char*)(&Bl[buf][0]) + wave * 1024;
    gll16(Ag0 + k0, AlB);
    gll16(Ag1 + k0, AlB + 4096);
    gll16(Bg0 + k0, BlB);
    gll16(Bg1 + k0, BlB + 4096);
  };

  f32x4 zero = {0.f, 0.f, 0.f, 0.f};
  f32x4 acc[4][4];
#pragma unroll
  for (int i = 0; i < 4; ++i)
#pragma unroll
    for (int j = 0; j < 4; ++j) acc[i][j] = zero;

  stage(0, 0);
  asm volatile("s_waitcnt vmcnt(0)" ::: "memory");
  __syncthreads();

  int cur = 0;
  for (int k0 = 0; k0 < K; k0 += 32) {
    if (k0 + 32 < K) stage(cur ^ 1, k0 + 32);   // prefetch next tile (in flight over MFMA)
    const u16* Ab = &Al[cur][0];
    const u16* Bb = &Bl[cur][0];
    short8 af[4], bf4[4];
#pragma unroll
    for (int i = 0; i < 4; ++i)
      af[i] = *(const short8*)(Ab + (wm + i * 16 + l15) * 32 + l4 * 8);
#pragma unroll
    for (int j = 0; j < 4; ++j)
      bf4[j] = *(const short8*)(Bb + (wn + j * 16 + l15) * 32 + l4 * 8);
#pragma unroll
    for (int i = 0; i < 4; ++i)
#pragma unroll
      for (int j = 0; j < 4; ++j)
        acc[i][j] = __builtin_amdgcn_mfma_f32_16x16x32_bf16(af[i], bf4[j], acc[i][j], 0, 0, 0);
    asm volatile("s_waitcnt vmcnt(0)" ::: "memory");
    __syncthreads();
    cur ^= 1;
  }

#pragma unroll
  for (int i = 0; i < 4; ++i)
#pragma unroll
    for (int j = 0; j < 4; ++j) {
      int col = n0 + wn + j * 16 + l15;
      float bv = (EPI == EPI_GELU || EPI == EPI_ADDBIAS) ? bias[col] : 0.f;
#pragma unroll
      for (int r = 0; r < 4; ++r) {
        int row = m0 + wm + i * 16 + l4 * 4 + r;
        float v = acc[i][j][r];
        if (EPI == EPI_STORE) {
          Cb[(size_t)row * N + col] = f2bf(v * alpha);
        } else if (EPI == EPI_QKV) {
          // Q,K,V are contiguous NXE-sized buffers starting at Cb
          u16* dst = Cb + (size_t)(col >> 9) * NXE;
          float al = (col < 512) ? alpha : 1.0f;
          dst[(size_t)row * D_ + (col & 511)] = f2bf(v * al);
        } else if (EPI == EPI_GELU) {
          Cb[(size_t)row * N + col] = f2bf(gelu_f(v + bv));
        } else if (EPI == EPI_ADD) {
          Cf[(size_t)row * N + col] += v;
        } else {
          Cf[(size_t)row * N + col] += v + bv;
        }
      }
    }
}

// ---------------- block key sums (bf16 K) ----------------
__global__ __launch_bounds__(64) void k_ksum(const u16* __restrict__ K,
                                             float* __restrict__ ksum) {
  int id = blockIdx.x;  // B*NB*H
  int h = id & (H_ - 1);
  int n = (id >> 3) & (NB_ - 1);
  int b = id >> 7;
  int f = threadIdx.x;
  float s = 0.f;
  const u16* kp = K + (((size_t)(b * S_ + n * BLK_) * H_) + h) * DH_ + f;
  for (int c = 0; c < BLK_; ++c) s += bf2f(kp[(size_t)c * H_ * DH_]);
  ksum[(((size_t)(b * NB_ + n) * H_) + h) * DH_ + f] = s;
}

// ---------------- sort-net logits ----------------
__global__ __launch_bounds__(256) void k_logits(const float* __restrict__ ksum,
                                                const float* __restrict__ sw,
                                                float* __restrict__ logits) {
  int idx = blockIdx.x * 256 + threadIdx.x;
  int m = idx & 15;
  int n = (idx >> 4) & 15;
  int h = (idx >> 8) & 7;
  int b = idx >> 11;
  const float* kp = ksum + (((size_t)(b * NB_ + n) * H_) + h) * DH_;
  const float* wp = sw + (size_t)h * DH_ * NB_ + m;
  float s = 0.f;
#pragma unroll
  for (int d = 0; d < DH_; ++d) s += kp[d] * wp[(size_t)d * NB_];
  logits[idx] = s;
}

// ---------------- sinkhorn ----------------
__global__ __launch_bounds__(256) void k_sinkhorn(const float* __restrict__ logits,
                                                  float* __restrict__ perm) {
  int bh = blockIdx.x;
  int tid = threadIdx.x;
  int i = tid >> 4, j = tid & 15;
  float la = logits[(size_t)bh * 256 + tid];
  __shared__ float buf[256];
  __shared__ float red[16];
  for (int it = 0; it < 8; ++it) {
    buf[tid] = la;
    __syncthreads();
    if (j == 0) {
      float m = buf[i * 16];
      for (int t = 1; t < 16; ++t) m = fmaxf(m, buf[i * 16 + t]);
      float s = 0.f;
      for (int t = 0; t < 16; ++t) s += expf(buf[i * 16 + t] - m);
      red[i] = m + logf(s);
    }
    __syncthreads();
    la -= red[i];
    buf[tid] = la;
    __syncthreads();
    if (tid < 16) {
      float m = buf[tid];
      for (int t = 1; t < 16; ++t) m = fmaxf(m, buf[t * 16 + tid]);
      float s = 0.f;
      for (int t = 0; t < 16; ++t) s += expf(buf[t * 16 + tid] - m);
      red[tid] = m + logf(s);
    }
    __syncthreads();
    la -= red[j];
    __syncthreads();
  }
  perm[(size_t)bh * 256 + tid] = expf(la);
}

// ---------------- permuted key/value blocks + sorted mask (bf16) ----------------
__global__ __launch_bounds__(256) void k_sortblocks(
    const float* __restrict__ perm, const u16* __restrict__ K,
    const u16* __restrict__ V, const int* __restrict__ tokens,
    u16* __restrict__ SK, u16* __restrict__ SV, float* __restrict__ smask) {
  int n = blockIdx.x, h = blockIdx.y, b = blockIdx.z;
  int tid = threadIdx.x;
  __shared__ float pr[NB_];
  if (tid < NB_) pr[tid] = perm[(((size_t)(b * H_ + h) * NB_) + n) * NB_ + tid];
  __syncthreads();
  for (int it = tid; it < 1024; it += 256) {
    int c = it >> 3;
    int f8 = (it & 7) * 8;
    float ak[8] = {}, av[8] = {};
#pragma unroll
    for (int m = 0; m < NB_; ++m) {
      float p = pr[m];
      size_t off = (((size_t)(b * S_ + m * BLK_ + c) * H_) + h) * DH_ + f8;
      short8 kv = *(const short8*)(K + off);
      short8 vv = *(const short8*)(V + off);
#pragma unroll
      for (int j = 0; j < 8; ++j) {
        ak[j] += p * bf2f((u16)kv[j]);
        av[j] += p * bf2f((u16)vv[j]);
      }
    }
    short8 ok, ov;
#pragma unroll
    for (int j = 0; j < 8; ++j) {
      ok[j] = (short)f2bf(ak[j]);
      ov[j] = (short)f2bf(av[j]);
    }
    size_t oo = (((size_t)(b * S_ + n * BLK_ + c) * H_) + h) * DH_ + f8;
    *(short8*)(SK + oo) = ok;
    *(short8*)(SV + oo) = ov;
  }
  if (tid < BLK_) {
    float s = 0.f;
#pragma unroll
    for (int m = 0; m < NB_; ++m)
      s += pr[m] * ((tokens[b * S_ + m * BLK_ + tid] > 0) ? 1.0f : 0.0f);
    smask[(((size_t)(b * H_ + h) * NB_) + n) * BLK_ + tid] = s;
  }
}

// ---------------- fused attention: scores + mask + softmax + PV (MFMA) ----------------
__global__ __launch_bounds__(512) void k_attn(
    const u16* __restrict__ Q, const u16* __restrict__ Kg, const u16* __restrict__ SK,
    const u16* __restrict__ Vg, const u16* __restrict__ SV,
    const int* __restrict__ tokens, const float* __restrict__ smask,
    u16* __restrict__ O) {
  int n = blockIdx.x, h = blockIdx.y, b = blockIdx.z;
  int tid = threadIdx.x;
  int lane = tid & 63;
  int w = tid >> 6;
  int l15 = lane & 15, l4 = lane >> 4;

  __shared__ u16 KV[16384];   // Kcat [256 kcat][64 dh] swizzled; later V^T [64][256]
  __shared__ u16 Pl[32768];   // P [128 q][256 k] bf16, q-XOR swizzled 8B slots
  __shared__ float sbias[256];

  // ---- V -> registers (issue early; LDS-write after QK phase, T14) ----
  short8 vreg[4];
  int vrow;
  {
    vrow = tid & 255;                 // kcat row
    int rl = vrow & 127;
    const u16* vsrc = (vrow < BLK_) ? Vg : SV;
    const u16* vbase = vsrc + (((size_t)(b * S_ + n * BLK_ + rl) * H_) + h) * DH_;
    int fh = (tid >> 8) * 8;
#pragma unroll
    for (int s = 0; s < 4; ++s)
      vreg[s] = *(const short8*)(vbase + s * 16 + fh);
  }

  // ---- Kcat -> LDS (global_load_lds, source pre-swizzled: rule #21) ----
#pragma unroll
  for (int s = 0; s < 4; ++s) {
    int c = s * 512 + tid;            // 16B chunk id, 0..2047
    int r = c >> 3;                   // kcat row
    int fs = (c & 7) ^ (r & 7);       // swizzled 16B slot in source
    const u16* ksrc = (r < BLK_) ? Kg : SK;
    gll16(ksrc + (((size_t)(b * S_ + n * BLK_ + (r & 127)) * H_) + h) * DH_ + fs * 8,
          (char*)KV + (s * 512 + w * 64) * 16);
  }

  // ---- Q fragments straight from global (B-operand, held in regs) ----
  short8 qf0, qf1;
  {
    const u16* qp = Q + (((size_t)(b * S_ + n * BLK_ + w * 16 + l15) * H_) + h) * DH_ + l4 * 8;
    qf0 = *(const short8*)(qp);
    qf1 = *(const short8*)(qp + 32);
  }

  // ---- mask bias ----
  if (tid < 256) {
    float mval = (tid < BLK_)
        ? ((tokens[b * S_ + n * BLK_ + tid] > 0) ? 1.f : 0.f)
        : smask[(((size_t)(b * H_ + h) * NB_) + n) * BLK_ + (tid - BLK_)];
    sbias[tid] = (mval > 0.5f) ? 0.f : NEGINF;
  }
  __syncthreads();

  // ---- QK^T (swapped): St[kcat][q] ----
  f32x4 zero = {0.f, 0.f, 0.f, 0.f};
  f32x4 st[16];
#pragma unroll
  for (int m = 0; m < 16; ++m) st[m] = zero;
#pragma unroll
  for (int m = 0; m < 16; ++m) {
    int arow = m * 16 + l15;
    const u16* kb = KV + arow * 64;
    int sw = arow & 7;
    short8 a0 = *(const short8*)(kb + ((l4 ^ sw) * 8));
    short8 a1 = *(const short8*)(kb + (((4 + l4) ^ sw) * 8));
    st[m] = __builtin_amdgcn_mfma_f32_16x16x32_bf16(a0, qf0, st[m], 0, 0, 0);
    st[m] = __builtin_amdgcn_mfma_f32_16x16x32_bf16(a1, qf1, st[m], 0, 0, 0);
  }

  // ---- softmax in-register ----
  float mx = -3.0e38f;
#pragma unroll
  for (int m = 0; m < 16; ++m)
#pragma unroll
    for (int r = 0; r < 4; ++r) {
      st[m][r] += sbias[m * 16 + l4 * 4 + r];
      mx = fmaxf(mx, st[m][r]);
    }
  mx = fmaxf(mx, __shfl_xor(mx, 16));
  mx = fmaxf(mx, __shfl_xor(mx, 32));
  float sum = 0.f;
#pragma unroll
  for (int m = 0; m < 16; ++m)
#pragma unroll
    for (int r = 0; r < 4; ++r) {
      float e = __expf(st[m][r] - mx);
      st[m][r] = e;
      sum += e;
    }
  sum += __shfl_xor(sum, 16);
  sum += __shfl_xor(sum, 32);
  float inv = 1.0f / sum;

  // ---- P -> LDS (bf16, q-XOR swizzle) ----
  int q = w * 16 + l15;
  int qx = q & 31;
#pragma unroll
  for (int m = 0; m < 16; ++m) {
    short4v p4;
#pragma unroll
    for (int r = 0; r < 4; ++r) p4[r] = (short)f2bf(st[m][r] * inv);
    int slot = (m * 4 + l4) ^ qx;
    *(short4v*)(Pl + q * 256 + slot * 4) = p4;
  }
  __syncthreads();

  // ---- V^T into KV (Kcat dead now); 16B-slot swizzle by (d&7) ----
  {
    int fh = (tid >> 8) * 8;
#pragma unroll
    for (int s = 0; s < 4; ++s) {
#pragma unroll
      for (int j = 0; j < 8; ++j) {
        int d = s * 16 + fh + j;
        KV[d * 256 + (((vrow >> 3) ^ (d & 7)) * 8) + (vrow & 7)] = (u16)vreg[s][j];
      }
    }
  }
  __syncthreads();

  // ---- PV: O[q][dh] = P · V ----
  f32x4 oacc[4];
#pragma unroll
  for (int nf = 0; nf < 4; ++nf) oacc[nf] = zero;
#pragma unroll
  for (int kk = 0; kk < 8; ++kk) {
    int s0 = (kk * 8 + l4 * 2) ^ qx;
    int s1 = (kk * 8 + l4 * 2 + 1) ^ qx;
    short4v a0 = *(const short4v*)(Pl + q * 256 + s0 * 4);
    short4v a1 = *(const short4v*)(Pl + q * 256 + s1 * 4);
    short8 af;
#pragma unroll
    for (int j = 0; j < 4; ++j) { af[j] = a0[j]; af[4 + j] = a1[j]; }
#pragma unroll
    for (int nf = 0; nf < 4; ++nf) {
      int d = nf * 16 + l15;
      short8 bf = *(const short8*)(KV + d * 256 + (((kk * 4 + l4) ^ (d & 7)) * 8));
      oacc[nf] = __builtin_amdgcn_mfma_f32_16x16x32_bf16(af, bf, oacc[nf], 0, 0, 0);
    }
  }

  // ---- store O (bf16) ----
  u16* ob = O + (((size_t)(b * S_ + n * BLK_) * H_) + h) * DH_;
#pragma unroll
  for (int nf = 0; nf < 4; ++nf) {
    int d = nf * 16 + l15;
#pragma unroll
    for (int r = 0; r < 4; ++r) {
      int qq = w * 16 + l4 * 4 + r;
      ob[(size_t)qq * (H_ * DH_) + d] = f2bf(oacc[nf][r]);
    }
  }
}

// ---------------- launch ----------------
extern "C" void kernel_launch(void* const* d_in, const int* in_sizes, int n_in,
                              void* d_out, int out_size, void* d_ws, size_t ws_size,
                              hipStream_t stream) {
  const int* tokens = (const int*)d_in[0];
  const float* embed = (const float*)d_in[1];
  const float* ln1_s = (const float*)d_in[2];
  const float* ln1_b = (const float*)d_in[3];
  const float* wq = (const float*)d_in[4];
  const float* wk = (const float*)d_in[5];
  const float* wv = (const float*)d_in[6];
  const float* wo = (const float*)d_in[7];
  const float* sortw = (const float*)d_in[8];
  const float* ln2_s = (const float*)d_in[9];
  const float* ln2_b = (const float*)d_in[10];
  const float* w1 = (const float*)d_in[11];
  const float* b1 = (const float*)d_in[12];
  const float* w2 = (const float*)d_in[13];
  const float* b2 = (const float*)d_in[14];
  const float* lnf_s = (const float*)d_in[15];
  const float* lnf_b = (const float*)d_in[16];
  float* out = (float*)d_out;

  const size_t NX = NXE;
  float* ws = (float*)d_ws;
  float* X = ws;                    // NX f32
  float* ATT = ws + NX;             // 4*NX f32 region; MLP hidden aliases here
  u16* HID = (u16*)ATT;
  u16* Hbf = (u16*)(ws + 5 * NX);   // NX bf16
  u16* Qb = Hbf + NX;               // Q,K,V contiguous (EPI_QKV relies on this)
  u16* Kb = Qb + NX;
  u16* Vb = Kb + NX;
  u16* SKb = Vb + NX;
  u16* SVb = SKb + NX;
  u16* Ob = Hbf;                    // alias: LN1 output dead by PV time
  float* KS = (float*)(SVb + NX);
  float* LG = KS + (size_t)B_ * NB_ * H_ * DH_;
  float* PM = LG + (size_t)B_ * H_ * NB_ * NB_;
  float* SM = PM + (size_t)B_ * H_ * NB_ * NB_;
  u16* WT = (u16*)(SM + (size_t)B_ * H_ * NB_ * BLK_);
  u16* wqkvT = WT;                                // [L][1536][512]
  u16* woT = wqkvT + (size_t)L_ * 3 * D_ * D_;    // [L][512][512]
  u16* w1T = woT + (size_t)L_ * D_ * D_;          // [L][2048][512]
  u16* w2T = w1T + (size_t)L_ * D_ * MLP_;        // [L][512][2048]

  const int rows = B_ * S_;
  const float scale = 0.125f;
  const size_t qkvStride = (size_t)3 * D_ * D_;

  // weight transposes (bf16, [N][K]); wq/wk/wv interleave into wqkvT rows 0/512/1024
  k_transp<<<dim3(16, 16, L_), 256, 0, stream>>>(wq, wqkvT, D_, D_, (size_t)D_ * D_, qkvStride);
  k_transp<<<dim3(16, 16, L_), 256, 0, stream>>>(wk, wqkvT + (size_t)512 * 512, D_, D_, (size_t)D_ * D_, qkvStride);
  k_transp<<<dim3(16, 16, L_), 256, 0, stream>>>(wv, wqkvT + (size_t)1024 * 512, D_, D_, (size_t)D_ * D_, qkvStride);
  k_transp<<<dim3(16, 16, L_), 256, 0, stream>>>(wo, woT, D_, D_, (size_t)D_ * D_, (size_t)D_ * D_);
  k_transp<<<dim3(16, 64, L_), 256, 0, stream>>>(w1, w1T, D_, MLP_, (size_t)D_ * MLP_, (size_t)MLP_ * D_);
  k_transp<<<dim3(64, 16, L_), 256, 0, stream>>>(w2, w2T, MLP_, D_, (size_t)MLP_ * D_, (size_t)D_ * MLP_);

  k_embed<<<B_ * S_, 128, 0, stream>>>(tokens, embed, X);

  for (int l = 0; l < L_; ++l) {
    k_ln<u16><<<rows / 4, 256, 0, stream>>>(X, ln1_s + l * D_, ln1_b + l * D_, Hbf, rows);
    dim3 gqkv(1536 / 128, rows / 128);   // fused QKV, N=1536
    k_mm<EPI_QKV><<<gqkv, 256, 0, stream>>>(Hbf, wqkvT + (size_t)l * qkvStride, nullptr, Qb, nullptr, rows, 1536, D_, scale);
    k_ksum<<<B_ * NB_ * H_, 64, 0, stream>>>(Kb, KS);
    k_logits<<<(B_ * H_ * NB_ * NB_) / 256, 256, 0, stream>>>(KS, sortw + (size_t)l * H_ * DH_ * NB_, LG);
    k_sinkhorn<<<B_ * H_, 256, 0, stream>>>(LG, PM);
    dim3 gatt(NB_, H_, B_);
    k_sortblocks<<<gatt, 256, 0, stream>>>(PM, Kb, Vb, tokens, SKb, SVb, SM);
    k_attn<<<gatt, 512, 0, stream>>>(Qb, Kb, SKb, Vb, SVb, tokens, SM, Ob);
    dim3 go(D_ / 128, rows / 128);
    k_mm<EPI_ADD><<<go, 256, 0, stream>>>(Ob, woT + (size_t)l * D_ * D_, nullptr, nullptr, X, rows, D_, D_, 1.0f);
    k_ln<u16><<<rows / 4, 256, 0, stream>>>(X, ln2_s + l * D_, ln2_b + l * D_, Hbf, rows);
    dim3 g2(MLP_ / 128, rows / 128);
    k_mm<EPI_GELU><<<g2, 256, 0, stream>>>(Hbf, w1T + (size_t)l * D_ * MLP_, b1 + (size_t)l * MLP_, HID, nullptr, rows, MLP_, D_, 1.0f);
    dim3 g3(D_ / 128, rows / 128);
    k_mm<EPI_ADDBIAS><<<g3, 256, 0, stream>>>(HID, w2T + (size_t)l * MLP_ * D_, b2 + (size_t)l * D_, nullptr, X, rows, D_, MLP_, 1.0f);
  }
  k_ln<float><<<rows / 4, 256, 0, stream>>>(X, lnf_s, lnf_b, out, rows);
}